// Round 1
// baseline (1976.453 us; speedup 1.0000x reference)
//
#include <hip/hip_runtime.h>
#include <hip/hip_bf16.h>
#include <cstdint>

typedef __bf16 bf16;
typedef __attribute__((ext_vector_type(8))) __bf16 bf16x8;
typedef __attribute__((ext_vector_type(4))) __bf16 bf16x4;
typedef __attribute__((ext_vector_type(4))) float f32x4;

#define N_NODES    65536
#define NUM_GRAPHS 512
#define MAX_N      192
#define D          512
#define H          8
#define DH         64

// ---------------- kernel 1: graph boundaries (lower_bound per graph id) ----------------
__global__ __launch_bounds__(256) void lb_kernel(const int* __restrict__ batch,
                                                 int* __restrict__ lb) {
    int g = blockIdx.x * 256 + threadIdx.x;
    if (g > NUM_GRAPHS) return;
    int lo = 0, hi = N_NODES;
    while (lo < hi) {
        int mid = (lo + hi) >> 1;
        if (batch[mid] < g) lo = mid + 1; else hi = mid;
    }
    lb[g] = lo;   // lb[g] = first node index with batch>=g; lb[512]=65536
}

// ---------------- kernel 2: fp32 -> bf16 convert ----------------
__global__ __launch_bounds__(256) void cvt_kernel(const float* __restrict__ src,
                                                  bf16* __restrict__ dst, int n) {
    int i = (blockIdx.x * 256 + threadIdx.x) * 4;
    if (i >= n) return;
    float4 v = *(const float4*)(src + i);
    bf16x4 o = {(bf16)v.x, (bf16)v.y, (bf16)v.z, (bf16)v.w};
    *(bf16x4*)(dst + i) = o;
}

// ---------------- kernel 3: P2[h][p][o] = sum_j gq[h*64+j]*wq[o,64p+j] ----------------
__global__ __launch_bounds__(256) void p2_kernel(const float* __restrict__ gq,
                                                 const float* __restrict__ wq,
                                                 float* __restrict__ P2) {
    int h = blockIdx.x, p = blockIdx.y;
    __shared__ float gs[64];
    if (threadIdx.x < 64) gs[threadIdx.x] = gq[h * 64 + threadIdx.x];
    __syncthreads();
    for (int o = threadIdx.x; o < D; o += 256) {
        const float* wr = wq + (size_t)o * D + p * 64;
        float acc = 0.f;
        #pragma unroll 16
        for (int j = 0; j < 64; j++) acc += gs[j] * wr[j];
        P2[(size_t)(h * 8 + p) * D + o] = acc;
    }
}

// ---------------- kernel 4: K/V projection GEMM (bf16 MFMA, shared A tile) ----------------
// C[i,o] = sum_d A[i,d]*W[o,d] + b[o], stored bf16. Tile: 128 rows x 64 cols, BK=32.
__global__ __launch_bounds__(256) void kv_gemm(const float* __restrict__ A,
                                               const bf16* __restrict__ Wk,
                                               const bf16* __restrict__ Wv,
                                               const float* __restrict__ bkb,
                                               const float* __restrict__ bvb,
                                               bf16* __restrict__ Kout,
                                               bf16* __restrict__ Vout) {
    const int i0 = blockIdx.x * 128;
    const int o0 = blockIdx.y * 64;
    __shared__ bf16 As[128 * 32];
    __shared__ bf16 Bk[64 * 32];
    __shared__ bf16 Bv[64 * 32];
    const int tid = threadIdx.x;
    const int lane = tid & 63;
    const int w = tid >> 6;            // wave 0..3 -> rows [w*32, w*32+32)
    const int fr = lane & 15;          // frag row/col within 16
    const int fq = lane >> 4;          // quad
    const int ar = tid >> 2;           // staging row 0..63
    const int ac = (tid & 3) * 8;      // staging col chunk

    f32x4 accK[2][4] = {};
    f32x4 accV[2][4] = {};

    for (int kt = 0; kt < D; kt += 32) {
        __syncthreads();
        {   // stage A tile (fp32 global -> bf16 LDS), rows ar and ar+64
            const float* s0 = A + (size_t)(i0 + ar) * D + kt + ac;
            float4 a0 = *(const float4*)s0;
            float4 a1 = *(const float4*)(s0 + 4);
            const float* s1 = s0 + (size_t)64 * D;
            float4 a2 = *(const float4*)s1;
            float4 a3 = *(const float4*)(s1 + 4);
            bf16x8 v0 = {(bf16)a0.x,(bf16)a0.y,(bf16)a0.z,(bf16)a0.w,
                         (bf16)a1.x,(bf16)a1.y,(bf16)a1.z,(bf16)a1.w};
            bf16x8 v1 = {(bf16)a2.x,(bf16)a2.y,(bf16)a2.z,(bf16)a2.w,
                         (bf16)a3.x,(bf16)a3.y,(bf16)a3.z,(bf16)a3.w};
            *(bf16x8*)(As + ar * 32 + ac) = v0;
            *(bf16x8*)(As + (ar + 64) * 32 + ac) = v1;
            // stage W tiles (already bf16)
            *(bf16x8*)(Bk + ar * 32 + ac) = *(const bf16x8*)(Wk + (size_t)(o0 + ar) * D + kt + ac);
            *(bf16x8*)(Bv + ar * 32 + ac) = *(const bf16x8*)(Wv + (size_t)(o0 + ar) * D + kt + ac);
        }
        __syncthreads();
        bf16x8 fa[2], fk[4], fv[4];
        #pragma unroll
        for (int mf = 0; mf < 2; mf++)
            fa[mf] = *(const bf16x8*)(As + (w * 32 + mf * 16 + fr) * 32 + fq * 8);
        #pragma unroll
        for (int nf = 0; nf < 4; nf++) {
            fk[nf] = *(const bf16x8*)(Bk + (nf * 16 + fr) * 32 + fq * 8);
            fv[nf] = *(const bf16x8*)(Bv + (nf * 16 + fr) * 32 + fq * 8);
        }
        #pragma unroll
        for (int mf = 0; mf < 2; mf++)
            #pragma unroll
            for (int nf = 0; nf < 4; nf++) {
                accK[mf][nf] = __builtin_amdgcn_mfma_f32_16x16x32_bf16(fa[mf], fk[nf], accK[mf][nf], 0, 0, 0);
                accV[mf][nf] = __builtin_amdgcn_mfma_f32_16x16x32_bf16(fa[mf], fv[nf], accV[mf][nf], 0, 0, 0);
            }
    }
    // epilogue: D layout col=lane&15, row=quad*4+r
    #pragma unroll
    for (int nf = 0; nf < 4; nf++) {
        int col = o0 + nf * 16 + fr;
        float bks = bkb[col], bvs = bvb[col];
        #pragma unroll
        for (int mf = 0; mf < 2; mf++) {
            int row = i0 + w * 32 + mf * 16 + fq * 4;
            #pragma unroll
            for (int r = 0; r < 4; r++) {
                Kout[(size_t)(row + r) * D + col] = (bf16)(accK[mf][nf][r] + bks);
                Vout[(size_t)(row + r) * D + col] = (bf16)(accV[mf][nf][r] + bvs);
            }
        }
    }
}

// ---------------- kernel 5: attention + pooling -> pooled_pre[g, 512] ----------------
__global__ __launch_bounds__(256) void attn_kernel(const bf16* __restrict__ Kb,
                                                   const bf16* __restrict__ Vb,
                                                   const float* __restrict__ P2,
                                                   const float* __restrict__ bq,
                                                   const int* __restrict__ lb,
                                                   float* __restrict__ pooled) {
    const int g = blockIdx.x;
    const int off = lb[g];
    const int n = min(lb[g + 1] - off, MAX_N);
    const int tid = threadIdx.x;
    const int lane = tid & 63;
    const int w = tid >> 6;

    __shared__ float Ksh[MAX_N * 68];          // stride 68 == 4 mod 32: same bank pattern as contiguous
    __shared__ float qrow[4][64];
    __shared__ float wbar[4][MAX_N];
    __shared__ float red[256];
    __shared__ unsigned char htab[MAX_N * 8];

    if (n == 0) {
        for (int j = tid; j < D; j += 256) pooled[(size_t)g * D + j] = 0.f;
        return;
    }
    for (int idx = tid; idx < n * 8; idx += 256) {
        int t = idx >> 3, p = idx & 7;
        htab[idx] = (unsigned char)((8 * t + p) / n);
    }
    const int nc = (n + 63) >> 6;

    for (int h = 0; h < H; h++) {
        __syncthreads();
        // stage K head-slice: Ksh[s][j] = fp32(K[off+s, h*64+j])
        for (int idx = tid; idx < n * 8; idx += 256) {
            int s = idx >> 3, jc = (idx & 7) * 8;
            bf16x8 kb8 = *(const bf16x8*)(Kb + (size_t)(off + s) * D + h * 64 + jc);
            float4 f0 = {(float)kb8[0], (float)kb8[1], (float)kb8[2], (float)kb8[3]};
            float4 f1 = {(float)kb8[4], (float)kb8[5], (float)kb8[6], (float)kb8[7]};
            float* dstp = Ksh + s * 68 + jc;
            *(float4*)dstp = f0;
            *(float4*)(dstp + 4) = f1;
        }
        __syncthreads();
        const float qb = bq[h * 64 + lane];
        float wb0 = 0.f, wb1 = 0.f, wb2 = 0.f;
        for (int t = w; t < n; t += 4) {
            // Q row on the fly: lane j computes Q[t, h*64+j]
            float qv = qb;
            #pragma unroll
            for (int p = 0; p < 8; p++) {
                int hh = htab[t * 8 + p];
                qv += P2[(size_t)(hh * 8 + p) * D + h * 64 + lane];
            }
            qrow[w][lane] = qv;
            float4 q4[16];
            #pragma unroll
            for (int jc = 0; jc < 16; jc++) q4[jc] = *(const float4*)(&qrow[w][jc * 4]);
            float sc[3] = {-1e30f, -1e30f, -1e30f};
            for (int c = 0; c < nc; c++) {
                int s = c * 64 + lane;
                const float* kr = Ksh + (s < n ? s : 0) * 68;
                float acc = 0.f;
                #pragma unroll
                for (int jc = 0; jc < 16; jc++) {
                    float4 k4 = *(const float4*)(kr + jc * 4);
                    acc += q4[jc].x * k4.x + q4[jc].y * k4.y + q4[jc].z * k4.z + q4[jc].w * k4.w;
                }
                sc[c] = (s < n) ? acc * 0.125f : -1e30f;
            }
            float m = fmaxf(sc[0], fmaxf(sc[1], sc[2]));
            #pragma unroll
            for (int o = 32; o >= 1; o >>= 1) m = fmaxf(m, __shfl_xor(m, o));
            float e0 = (sc[0] > -1e29f) ? __expf(sc[0] - m) : 0.f;
            float e1 = (sc[1] > -1e29f) ? __expf(sc[1] - m) : 0.f;
            float e2 = (sc[2] > -1e29f) ? __expf(sc[2] - m) : 0.f;
            float rs = e0 + e1 + e2;
            #pragma unroll
            for (int o = 32; o >= 1; o >>= 1) rs += __shfl_xor(rs, o);
            float inv = 1.0f / rs;
            wb0 += e0 * inv; wb1 += e1 * inv; wb2 += e2 * inv;
        }
        wbar[w][lane] = wb0;
        wbar[w][64 + lane] = wb1;
        wbar[w][128 + lane] = wb2;
        __syncthreads();
        if (tid < n)
            wbar[0][tid] = (wbar[0][tid] + wbar[1][tid] + wbar[2][tid] + wbar[3][tid]) / (float)n;
        __syncthreads();
        {   // pooled_pre[h*64+j] = sum_s wbar[s] * V[off+s, h*64+j]
            float acc = 0.f;
            for (int s = w; s < n; s += 4)
                acc += wbar[0][s] * (float)Vb[(size_t)(off + s) * D + h * 64 + lane];
            red[tid] = acc;
            __syncthreads();
            if (tid < 64)
                pooled[(size_t)g * D + h * 64 + tid] = red[tid] + red[64 + tid] + red[128 + tid] + red[192 + tid];
        }
    }
}

// ---------------- kernels 6/7: small projections ----------------
__global__ __launch_bounds__(256) void proj_o(const float* __restrict__ x_in,
                                              const float* __restrict__ W,
                                              const float* __restrict__ b,
                                              const int* __restrict__ lb,
                                              float* __restrict__ y) {
    const int g = blockIdx.x;
    __shared__ float xs[D];
    for (int d0 = threadIdx.x; d0 < D; d0 += 256) xs[d0] = x_in[(size_t)g * D + d0];
    __syncthreads();
    const int n = lb[g + 1] - lb[g];
    for (int o = threadIdx.x; o < D; o += 256) {
        const float* wr = W + (size_t)o * D;
        float acc = b[o];
        for (int d0 = 0; d0 < D; d0 += 4) {
            float4 wv = *(const float4*)(wr + d0);
            acc += xs[d0] * wv.x + xs[d0 + 1] * wv.y + xs[d0 + 2] * wv.z + xs[d0 + 3] * wv.w;
        }
        y[(size_t)g * D + o] = (n > 0) ? acc : 0.f;   // n==0: pooled rows are all-masked -> 0
    }
}

__global__ __launch_bounds__(256) void proj_p(const float* __restrict__ x_in,
                                              const float* __restrict__ W,
                                              const float* __restrict__ b,
                                              float* __restrict__ y) {
    const int g = blockIdx.x;
    __shared__ float xs[D];
    for (int d0 = threadIdx.x; d0 < D; d0 += 256) xs[d0] = x_in[(size_t)g * D + d0];
    __syncthreads();
    for (int o = threadIdx.x; o < D; o += 256) {
        const float* wr = W + (size_t)o * D;
        float acc = b[o];
        for (int d0 = 0; d0 < D; d0 += 4) {
            float4 wv = *(const float4*)(wr + d0);
            acc += xs[d0] * wv.x + xs[d0 + 1] * wv.y + xs[d0 + 2] * wv.z + xs[d0 + 3] * wv.w;
        }
        y[(size_t)g * D + o] = fmaxf(acc, 0.f);
    }
}

extern "C" void kernel_launch(void* const* d_in, const int* in_sizes, int n_in,
                              void* d_out, int out_size, void* d_ws, size_t ws_size,
                              hipStream_t stream) {
    const float* nf    = (const float*)d_in[0];
    const int*   batch = (const int*)d_in[1];
    const float* gq    = (const float*)d_in[2];
    const float* wq    = (const float*)d_in[3];
    const float* bq    = (const float*)d_in[4];
    const float* wk    = (const float*)d_in[5];
    const float* bk    = (const float*)d_in[6];
    const float* wv    = (const float*)d_in[7];
    const float* bv    = (const float*)d_in[8];
    const float* wo    = (const float*)d_in[9];
    const float* bo    = (const float*)d_in[10];
    const float* wp    = (const float*)d_in[11];
    const float* bp    = (const float*)d_in[12];
    float* out = (float*)d_out;

    // workspace layout (~131.2 MB total)
    char* ws = (char*)d_ws;
    bf16* Kbf = (bf16*)ws;                                     // 64 MiB
    bf16* Vbf = (bf16*)(ws + (size_t)N_NODES * D * 2);         // 64 MiB
    char* p = ws + (size_t)N_NODES * D * 4;
    int*  lb  = (int*)p;       p += 4096;                      // 513 ints
    bf16* Wkb = (bf16*)p;      p += (size_t)D * D * 2;         // 512 KiB
    bf16* Wvb = (bf16*)p;      p += (size_t)D * D * 2;         // 512 KiB
    float* P2 = (float*)p;     p += (size_t)64 * D * 4;        // 128 KiB
    float* pooled = (float*)p; p += (size_t)NUM_GRAPHS * D * 4;// 1 MiB
    float* tmp = (float*)p;    p += (size_t)NUM_GRAPHS * D * 4;// 1 MiB

    lb_kernel<<<3, 256, 0, stream>>>(batch, lb);
    cvt_kernel<<<(D * D / 4) / 256, 256, 0, stream>>>(wk, Wkb, D * D);
    cvt_kernel<<<(D * D / 4) / 256, 256, 0, stream>>>(wv, Wvb, D * D);
    p2_kernel<<<dim3(8, 8), 256, 0, stream>>>(gq, wq, P2);
    kv_gemm<<<dim3(N_NODES / 128, D / 64), 256, 0, stream>>>(nf, Wkb, Wvb, bk, bv, Kbf, Vbf);
    attn_kernel<<<NUM_GRAPHS, 256, 0, stream>>>(Kbf, Vbf, P2, bq, lb, pooled);
    proj_o<<<NUM_GRAPHS, 256, 0, stream>>>(pooled, wo, bo, lb, tmp);
    proj_p<<<NUM_GRAPHS, 256, 0, stream>>>(tmp, wp, bp, out);
}

// Round 2
// 849.455 us; speedup vs baseline: 2.3267x; 2.3267x over previous
//
#include <hip/hip_runtime.h>
#include <hip/hip_bf16.h>
#include <cstdint>

typedef __bf16 bf16;
typedef __attribute__((ext_vector_type(8))) __bf16 bf16x8;
typedef __attribute__((ext_vector_type(4))) __bf16 bf16x4;
typedef __attribute__((ext_vector_type(4))) float f32x4;

#define N_NODES    65536
#define NUM_GRAPHS 512
#define MAX_N      192
#define D          512
#define H          8
#define DH         64
#define UMAX       64   // hard bound on distinct Q-row patterns (math bound is 57)
#define USTRIDE    132  // ints per graph in udata: [0]=nu, [1..64]=pat, [65..128]=count

// ---------------- kernel 1: graph boundaries (lower_bound per graph id) ----------------
__global__ __launch_bounds__(256) void lb_kernel(const int* __restrict__ batch,
                                                 int* __restrict__ lb) {
    int g = blockIdx.x * 256 + threadIdx.x;
    if (g > NUM_GRAPHS) return;
    int lo = 0, hi = N_NODES;
    while (lo < hi) {
        int mid = (lo + hi) >> 1;
        if (batch[mid] < g) lo = mid + 1; else hi = mid;
    }
    lb[g] = lo;
}

// ---------------- kernel 1b: per-graph unique Q-row patterns ----------------
// pattern(t) = sum_p ((8t+p)/n) << (3p)  (24 bits). Monotone in t -> run-length encode.
__global__ __launch_bounds__(192) void dedup_kernel(const int* __restrict__ lb,
                                                    int* __restrict__ udata) {
    const int g = blockIdx.x;
    const int off = lb[g];
    const int n = min(lb[g + 1] - off, MAX_N);
    __shared__ int keys[MAX_N];
    const int t = threadIdx.x;
    if (t < n) {
        unsigned un = (unsigned)n;
        int key = 0;
        #pragma unroll
        for (int p = 0; p < 8; p++) key |= (int)(((unsigned)(8 * t + p)) / un) << (3 * p);
        keys[t] = key;
    }
    __syncthreads();
    if (t == 0) {
        int* base = udata + (size_t)g * USTRIDE;
        int nu = 0;
        for (int s = 0; s < n; s++) {
            if (s == 0 || keys[s] != keys[s - 1]) {
                if (nu < UMAX) { base[1 + nu] = keys[s]; base[65 + nu] = 0; nu++; }
            }
            base[65 + (nu - 1)] += 1;
        }
        base[0] = nu;
    }
}

// ---------------- kernel 2: fp32 -> bf16 convert ----------------
__global__ __launch_bounds__(256) void cvt_kernel(const float* __restrict__ src,
                                                  bf16* __restrict__ dst, int n) {
    int i = (blockIdx.x * 256 + threadIdx.x) * 4;
    if (i >= n) return;
    float4 v = *(const float4*)(src + i);
    bf16x4 o = {(bf16)v.x, (bf16)v.y, (bf16)v.z, (bf16)v.w};
    *(bf16x4*)(dst + i) = o;
}

// ---------------- kernel 3: P2[h][p][o] = sum_j gq[h*64+j]*wq[o,64p+j] ----------------
__global__ __launch_bounds__(256) void p2_kernel(const float* __restrict__ gq,
                                                 const float* __restrict__ wq,
                                                 float* __restrict__ P2) {
    int h = blockIdx.x, p = blockIdx.y;
    __shared__ float gs[64];
    if (threadIdx.x < 64) gs[threadIdx.x] = gq[h * 64 + threadIdx.x];
    __syncthreads();
    for (int o = threadIdx.x; o < D; o += 256) {
        const float* wr = wq + (size_t)o * D + p * 64;
        float acc = 0.f;
        #pragma unroll 16
        for (int j = 0; j < 64; j++) acc += gs[j] * wr[j];
        P2[(size_t)(h * 8 + p) * D + o] = acc;
    }
}

// ---------------- kernel 4: K/V projection GEMM (bf16 MFMA, shared A tile) ----------------
__global__ __launch_bounds__(256) void kv_gemm(const float* __restrict__ A,
                                               const bf16* __restrict__ Wk,
                                               const bf16* __restrict__ Wv,
                                               const float* __restrict__ bkb,
                                               const float* __restrict__ bvb,
                                               bf16* __restrict__ Kout,
                                               bf16* __restrict__ Vout) {
    const int i0 = blockIdx.x * 128;
    const int o0 = blockIdx.y * 64;
    __shared__ bf16 As[128 * 32];
    __shared__ bf16 Bk[64 * 32];
    __shared__ bf16 Bv[64 * 32];
    const int tid = threadIdx.x;
    const int lane = tid & 63;
    const int w = tid >> 6;
    const int fr = lane & 15;
    const int fq = lane >> 4;
    const int ar = tid >> 2;
    const int ac = (tid & 3) * 8;

    f32x4 accK[2][4] = {};
    f32x4 accV[2][4] = {};

    for (int kt = 0; kt < D; kt += 32) {
        __syncthreads();
        {
            const float* s0 = A + (size_t)(i0 + ar) * D + kt + ac;
            float4 a0 = *(const float4*)s0;
            float4 a1 = *(const float4*)(s0 + 4);
            const float* s1 = s0 + (size_t)64 * D;
            float4 a2 = *(const float4*)s1;
            float4 a3 = *(const float4*)(s1 + 4);
            bf16x8 v0 = {(bf16)a0.x,(bf16)a0.y,(bf16)a0.z,(bf16)a0.w,
                         (bf16)a1.x,(bf16)a1.y,(bf16)a1.z,(bf16)a1.w};
            bf16x8 v1 = {(bf16)a2.x,(bf16)a2.y,(bf16)a2.z,(bf16)a2.w,
                         (bf16)a3.x,(bf16)a3.y,(bf16)a3.z,(bf16)a3.w};
            *(bf16x8*)(As + ar * 32 + ac) = v0;
            *(bf16x8*)(As + (ar + 64) * 32 + ac) = v1;
            *(bf16x8*)(Bk + ar * 32 + ac) = *(const bf16x8*)(Wk + (size_t)(o0 + ar) * D + kt + ac);
            *(bf16x8*)(Bv + ar * 32 + ac) = *(const bf16x8*)(Wv + (size_t)(o0 + ar) * D + kt + ac);
        }
        __syncthreads();
        bf16x8 fa[2], fk[4], fv[4];
        #pragma unroll
        for (int mf = 0; mf < 2; mf++)
            fa[mf] = *(const bf16x8*)(As + (w * 32 + mf * 16 + fr) * 32 + fq * 8);
        #pragma unroll
        for (int nf = 0; nf < 4; nf++) {
            fk[nf] = *(const bf16x8*)(Bk + (nf * 16 + fr) * 32 + fq * 8);
            fv[nf] = *(const bf16x8*)(Bv + (nf * 16 + fr) * 32 + fq * 8);
        }
        #pragma unroll
        for (int mf = 0; mf < 2; mf++)
            #pragma unroll
            for (int nf = 0; nf < 4; nf++) {
                accK[mf][nf] = __builtin_amdgcn_mfma_f32_16x16x32_bf16(fa[mf], fk[nf], accK[mf][nf], 0, 0, 0);
                accV[mf][nf] = __builtin_amdgcn_mfma_f32_16x16x32_bf16(fa[mf], fv[nf], accV[mf][nf], 0, 0, 0);
            }
    }
    #pragma unroll
    for (int nf = 0; nf < 4; nf++) {
        int col = o0 + nf * 16 + fr;
        float bks = bkb[col], bvs = bvb[col];
        #pragma unroll
        for (int mf = 0; mf < 2; mf++) {
            int row = i0 + w * 32 + mf * 16 + fq * 4;
            #pragma unroll
            for (int r = 0; r < 4; r++) {
                Kout[(size_t)(row + r) * D + col] = (bf16)(accK[mf][nf][r] + bks);
                Vout[(size_t)(row + r) * D + col] = (bf16)(accV[mf][nf][r] + bvs);
            }
        }
    }
}

// ---------------- kernel 5: attention + pooling, one block per (head, graph) ----------------
__global__ __launch_bounds__(256) void attn_kernel(const bf16* __restrict__ Kb,
                                                   const bf16* __restrict__ Vb,
                                                   const float* __restrict__ P2,
                                                   const float* __restrict__ bq,
                                                   const int* __restrict__ lb,
                                                   const int* __restrict__ udata,
                                                   float* __restrict__ pooled) {
    const int h = blockIdx.x;
    const int g = blockIdx.y;
    const int off = lb[g];
    const int n = min(lb[g + 1] - off, MAX_N);
    const int tid = threadIdx.x;
    const int lane = tid & 63;
    const int w = tid >> 6;

    __shared__ float Ksh[MAX_N * 68];   // stride 68: conflict-free (same bank pattern as contiguous)
    __shared__ float Qh[16][64];
    __shared__ float wacc[4][MAX_N];
    __shared__ float red[256];
    __shared__ int upat_l[UMAX];
    __shared__ int ucnt_l[UMAX];
    __shared__ int nu_s;

    if (n == 0) {
        if (tid < 64) pooled[(size_t)g * D + h * 64 + tid] = 0.f;
        return;
    }
    const int* ubase = udata + (size_t)g * USTRIDE;
    if (tid == 0) nu_s = ubase[0];
    if (tid < 64) { upat_l[tid] = ubase[1 + tid]; ucnt_l[tid] = ubase[65 + tid]; }
    // zero wacc (wave-private rows)
    wacc[w][lane] = 0.f; wacc[w][64 + lane] = 0.f; wacc[w][128 + lane] = 0.f;

    // stage K head-slice: Ksh[s][j] = fp32(K[off+s, h*64+j])
    for (int idx = tid; idx < n * 8; idx += 256) {
        int s = idx >> 3, jc = (idx & 7) * 8;
        bf16x8 kb8 = *(const bf16x8*)(Kb + (size_t)(off + s) * D + h * 64 + jc);
        float4 f0 = {(float)kb8[0], (float)kb8[1], (float)kb8[2], (float)kb8[3]};
        float4 f1 = {(float)kb8[4], (float)kb8[5], (float)kb8[6], (float)kb8[7]};
        float* dstp = Ksh + s * 68 + jc;
        *(float4*)dstp = f0;
        *(float4*)(dstp + 4) = f1;
    }
    __syncthreads();
    const int nu = nu_s;
    const int nc = (n + 63) >> 6;
    const float inv_n = 1.0f / (float)n;

    for (int c0 = 0; c0 < nu; c0 += 16) {
        const int nuc = min(16, nu - c0);
        if (c0) __syncthreads();          // previous chunk done reading Qh
        for (int idx = tid; idx < nuc * 64; idx += 256) {
            int ul = idx >> 6, j = idx & 63;
            int pat = upat_l[c0 + ul];
            float val = bq[h * 64 + j];
            #pragma unroll
            for (int p = 0; p < 8; p++) {
                int hp = (pat >> (3 * p)) & 7;
                val += P2[(size_t)(hp * 8 + p) * D + h * 64 + j];
            }
            Qh[ul][j] = val;
        }
        __syncthreads();
        for (int ul = w; ul < nuc; ul += 4) {
            float4 q4[16];
            #pragma unroll
            for (int jc = 0; jc < 16; jc++) q4[jc] = *(const float4*)(&Qh[ul][jc * 4]);
            float sc[3] = {-1e30f, -1e30f, -1e30f};
            for (int c = 0; c < nc; c++) {
                int s = c * 64 + lane;
                const float* kr = Ksh + (s < n ? s : 0) * 68;
                float acc = 0.f;
                #pragma unroll
                for (int jc = 0; jc < 16; jc++) {
                    float4 k4 = *(const float4*)(kr + jc * 4);
                    acc += q4[jc].x * k4.x + q4[jc].y * k4.y + q4[jc].z * k4.z + q4[jc].w * k4.w;
                }
                sc[c] = (s < n) ? acc * 0.125f : -1e30f;
            }
            float m = fmaxf(sc[0], fmaxf(sc[1], sc[2]));
            #pragma unroll
            for (int o = 32; o >= 1; o >>= 1) m = fmaxf(m, __shfl_xor(m, o));
            float e0 = (sc[0] > -1e29f) ? __expf(sc[0] - m) : 0.f;
            float e1 = (sc[1] > -1e29f) ? __expf(sc[1] - m) : 0.f;
            float e2 = (sc[2] > -1e29f) ? __expf(sc[2] - m) : 0.f;
            float rs = e0 + e1 + e2;
            #pragma unroll
            for (int o = 32; o >= 1; o >>= 1) rs += __shfl_xor(rs, o);
            float wf = (float)ucnt_l[c0 + ul] * inv_n / rs;
            wacc[w][lane] += e0 * wf;
            wacc[w][64 + lane] += e1 * wf;
            wacc[w][128 + lane] += e2 * wf;
        }
    }
    __syncthreads();
    // pooled[g, h*64+j] = sum_s wbar[s] * V[off+s, h*64+j]
    float acc = 0.f;
    for (int s = w; s < n; s += 4) {
        float wv = wacc[0][s] + wacc[1][s] + wacc[2][s] + wacc[3][s];
        acc += wv * (float)Vb[(size_t)(off + s) * D + h * 64 + lane];
    }
    red[tid] = acc;
    __syncthreads();
    if (tid < 64)
        pooled[(size_t)g * D + h * 64 + tid] = red[tid] + red[64 + tid] + red[128 + tid] + red[192 + tid];
}

// ---------------- kernels 6/7: small projections ----------------
__global__ __launch_bounds__(256) void proj_o(const float* __restrict__ x_in,
                                              const float* __restrict__ W,
                                              const float* __restrict__ b,
                                              const int* __restrict__ lb,
                                              float* __restrict__ y) {
    const int g = blockIdx.x;
    __shared__ float xs[D];
    for (int d0 = threadIdx.x; d0 < D; d0 += 256) xs[d0] = x_in[(size_t)g * D + d0];
    __syncthreads();
    const int n = lb[g + 1] - lb[g];
    for (int o = threadIdx.x; o < D; o += 256) {
        const float* wr = W + (size_t)o * D;
        float acc = b[o];
        for (int d0 = 0; d0 < D; d0 += 4) {
            float4 wv = *(const float4*)(wr + d0);
            acc += xs[d0] * wv.x + xs[d0 + 1] * wv.y + xs[d0 + 2] * wv.z + xs[d0 + 3] * wv.w;
        }
        y[(size_t)g * D + o] = (n > 0) ? acc : 0.f;
    }
}

__global__ __launch_bounds__(256) void proj_p(const float* __restrict__ x_in,
                                              const float* __restrict__ W,
                                              const float* __restrict__ b,
                                              float* __restrict__ y) {
    const int g = blockIdx.x;
    __shared__ float xs[D];
    for (int d0 = threadIdx.x; d0 < D; d0 += 256) xs[d0] = x_in[(size_t)g * D + d0];
    __syncthreads();
    for (int o = threadIdx.x; o < D; o += 256) {
        const float* wr = W + (size_t)o * D;
        float acc = b[o];
        for (int d0 = 0; d0 < D; d0 += 4) {
            float4 wv = *(const float4*)(wr + d0);
            acc += xs[d0] * wv.x + xs[d0 + 1] * wv.y + xs[d0 + 2] * wv.z + xs[d0 + 3] * wv.w;
        }
        y[(size_t)g * D + o] = fmaxf(acc, 0.f);
    }
}

extern "C" void kernel_launch(void* const* d_in, const int* in_sizes, int n_in,
                              void* d_out, int out_size, void* d_ws, size_t ws_size,
                              hipStream_t stream) {
    const float* nf    = (const float*)d_in[0];
    const int*   batch = (const int*)d_in[1];
    const float* gq    = (const float*)d_in[2];
    const float* wq    = (const float*)d_in[3];
    const float* bq    = (const float*)d_in[4];
    const float* wk    = (const float*)d_in[5];
    const float* bk    = (const float*)d_in[6];
    const float* wv    = (const float*)d_in[7];
    const float* bv    = (const float*)d_in[8];
    const float* wo    = (const float*)d_in[9];
    const float* bo    = (const float*)d_in[10];
    const float* wp    = (const float*)d_in[11];
    const float* bp    = (const float*)d_in[12];
    float* out = (float*)d_out;

    // workspace layout (~131.3 MB total)
    char* ws = (char*)d_ws;
    bf16* Kbf = (bf16*)ws;                                     // 64 MiB
    bf16* Vbf = (bf16*)(ws + (size_t)N_NODES * D * 2);         // 64 MiB
    char* p = ws + (size_t)N_NODES * D * 4;
    int*  lb  = (int*)p;       p += 4096;
    bf16* Wkb = (bf16*)p;      p += (size_t)D * D * 2;
    bf16* Wvb = (bf16*)p;      p += (size_t)D * D * 2;
    float* P2 = (float*)p;     p += (size_t)64 * D * 4;
    float* pooled = (float*)p; p += (size_t)NUM_GRAPHS * D * 4;
    float* tmp = (float*)p;    p += (size_t)NUM_GRAPHS * D * 4;
    // udata aliases tmp: dedup writes -> attn reads -> proj_o overwrites tmp afterwards.
    int* udata = (int*)tmp;    // 512*132*4 = 270 KB <= 1 MiB

    lb_kernel<<<3, 256, 0, stream>>>(batch, lb);
    dedup_kernel<<<NUM_GRAPHS, 192, 0, stream>>>(lb, udata);
    cvt_kernel<<<(D * D / 4) / 256, 256, 0, stream>>>(wk, Wkb, D * D);
    cvt_kernel<<<(D * D / 4) / 256, 256, 0, stream>>>(wv, Wvb, D * D);
    p2_kernel<<<dim3(8, 8), 256, 0, stream>>>(gq, wq, P2);
    kv_gemm<<<dim3(N_NODES / 128, D / 64), 256, 0, stream>>>(nf, Wkb, Wvb, bk, bv, Kbf, Vbf);
    attn_kernel<<<dim3(H, NUM_GRAPHS), 256, 0, stream>>>(Kbf, Vbf, P2, bq, lb, udata, pooled);
    proj_o<<<NUM_GRAPHS, 256, 0, stream>>>(pooled, wo, bo, lb, tmp);
    proj_p<<<NUM_GRAPHS, 256, 0, stream>>>(tmp, wp, bp, out);
}

// Round 3
// 593.686 us; speedup vs baseline: 3.3291x; 1.4308x over previous
//
#include <hip/hip_runtime.h>
#include <hip/hip_bf16.h>
#include <cstdint>

typedef __bf16 bf16;
typedef __attribute__((ext_vector_type(8))) __bf16 bf16x8;
typedef __attribute__((ext_vector_type(4))) __bf16 bf16x4;
typedef __attribute__((ext_vector_type(4))) float f32x4;

#define N_NODES    65536
#define NUM_GRAPHS 512
#define MAX_N      192
#define D          512
#define H          8
#define DH         64
#define UMAX       64   // hard bound on distinct Q-row patterns (math bound is 57)
#define USTRIDE    132  // ints per graph in udata: [0]=nu, [1..64]=pat, [65..128]=count
#define QSTRIDE    80   // bf16 stride for Q tile rows (16B-aligned, de-conflicted)

// ---------------- kernel 1: graph boundaries ----------------
__global__ __launch_bounds__(256) void lb_kernel(const int* __restrict__ batch,
                                                 int* __restrict__ lb) {
    int g = blockIdx.x * 256 + threadIdx.x;
    if (g > NUM_GRAPHS) return;
    int lo = 0, hi = N_NODES;
    while (lo < hi) {
        int mid = (lo + hi) >> 1;
        if (batch[mid] < g) lo = mid + 1; else hi = mid;
    }
    lb[g] = lo;
}

// ---------------- kernel 1b: per-graph unique Q-row patterns ----------------
__global__ __launch_bounds__(192) void dedup_kernel(const int* __restrict__ lb,
                                                    int* __restrict__ udata) {
    const int g = blockIdx.x;
    const int off = lb[g];
    const int n = min(lb[g + 1] - off, MAX_N);
    __shared__ int keys[MAX_N];
    const int t = threadIdx.x;
    if (t < n) {
        unsigned un = (unsigned)n;
        int key = 0;
        #pragma unroll
        for (int p = 0; p < 8; p++) key |= (int)(((unsigned)(8 * t + p)) / un) << (3 * p);
        keys[t] = key;
    }
    __syncthreads();
    if (t == 0) {
        int* base = udata + (size_t)g * USTRIDE;
        int nu = 0;
        for (int s = 0; s < n; s++) {
            if (s == 0 || keys[s] != keys[s - 1]) {
                if (nu < UMAX) { base[1 + nu] = keys[s]; base[65 + nu] = 0; nu++; }
            }
            base[65 + (nu - 1)] += 1;
        }
        base[0] = nu;
    }
}

// ---------------- kernel 2: fp32 -> bf16 convert ----------------
__global__ __launch_bounds__(256) void cvt_kernel(const float* __restrict__ src,
                                                  bf16* __restrict__ dst, int n) {
    int i = (blockIdx.x * 256 + threadIdx.x) * 4;
    if (i >= n) return;
    float4 v = *(const float4*)(src + i);
    bf16x4 o = {(bf16)v.x, (bf16)v.y, (bf16)v.z, (bf16)v.w};
    *(bf16x4*)(dst + i) = o;
}

// ---------------- kernel 3: P2[h][p][o] = sum_j gq[h*64+j]*wq[o,64p+j] ----------------
__global__ __launch_bounds__(256) void p2_kernel(const float* __restrict__ gq,
                                                 const float* __restrict__ wq,
                                                 float* __restrict__ P2) {
    int h = blockIdx.x, p = blockIdx.y;
    __shared__ float gs[64];
    if (threadIdx.x < 64) gs[threadIdx.x] = gq[h * 64 + threadIdx.x];
    __syncthreads();
    for (int o = threadIdx.x; o < D; o += 256) {
        const float* wr = wq + (size_t)o * D + p * 64;
        float acc = 0.f;
        #pragma unroll 16
        for (int j = 0; j < 64; j++) acc += gs[j] * wr[j];
        P2[(size_t)(h * 8 + p) * D + o] = acc;
    }
}

// ---------------- kernel 4: K/V projection GEMM, 64x128 tile ----------------
// C[i,o] = sum_d A[i,d]*W[o,d] + b[o] for both (Wk,bk)->Kout and (Wv,bv)->Vout.
__global__ __launch_bounds__(256) void kv_gemm(const float* __restrict__ A,
                                               const bf16* __restrict__ Wk,
                                               const bf16* __restrict__ Wv,
                                               const float* __restrict__ bkb,
                                               const float* __restrict__ bvb,
                                               bf16* __restrict__ Kout,
                                               bf16* __restrict__ Vout) {
    const int i0 = blockIdx.x * 64;
    const int o0 = blockIdx.y * 128;
    __shared__ bf16 As[64 * 32];    // 4 KB
    __shared__ bf16 Bks[128 * 32];  // 8 KB
    __shared__ bf16 Bvs[128 * 32];  // 8 KB
    const int tid = threadIdx.x;
    const int lane = tid & 63;
    const int w = tid >> 6;          // wave -> col group [w*32, w*32+32)
    const int fr = lane & 15;
    const int quad = lane >> 4;
    const int arow = tid >> 2;       // 0..63
    const int acol = (tid & 3) * 8;  // 8 fp32 per thread
    const int brow = tid >> 1;       // 0..127
    const int bcol = (tid & 1) * 16; // 16 bf16 per thread

    f32x4 aK[4][2] = {};
    f32x4 aV[4][2] = {};

    for (int kt = 0; kt < D; kt += 32) {
        __syncthreads();
        {
            const float* ap = A + (size_t)(i0 + arow) * D + kt + acol;
            float4 x0 = *(const float4*)ap;
            float4 x1 = *(const float4*)(ap + 4);
            bf16x8 v = {(bf16)x0.x,(bf16)x0.y,(bf16)x0.z,(bf16)x0.w,
                        (bf16)x1.x,(bf16)x1.y,(bf16)x1.z,(bf16)x1.w};
            *(bf16x8*)(As + arow * 32 + acol) = v;
            const bf16* kp = Wk + (size_t)(o0 + brow) * D + kt + bcol;
            const bf16* vp = Wv + (size_t)(o0 + brow) * D + kt + bcol;
            *(bf16x8*)(Bks + brow * 32 + bcol)     = *(const bf16x8*)kp;
            *(bf16x8*)(Bks + brow * 32 + bcol + 8) = *(const bf16x8*)(kp + 8);
            *(bf16x8*)(Bvs + brow * 32 + bcol)     = *(const bf16x8*)vp;
            *(bf16x8*)(Bvs + brow * 32 + bcol + 8) = *(const bf16x8*)(vp + 8);
        }
        __syncthreads();
        bf16x8 fa[4], fk[2], fv[2];
        #pragma unroll
        for (int mf = 0; mf < 4; mf++)
            fa[mf] = *(const bf16x8*)(As + (mf * 16 + fr) * 32 + quad * 8);
        #pragma unroll
        for (int nf = 0; nf < 2; nf++) {
            fk[nf] = *(const bf16x8*)(Bks + (w * 32 + nf * 16 + fr) * 32 + quad * 8);
            fv[nf] = *(const bf16x8*)(Bvs + (w * 32 + nf * 16 + fr) * 32 + quad * 8);
        }
        #pragma unroll
        for (int mf = 0; mf < 4; mf++)
            #pragma unroll
            for (int nf = 0; nf < 2; nf++) {
                aK[mf][nf] = __builtin_amdgcn_mfma_f32_16x16x32_bf16(fa[mf], fk[nf], aK[mf][nf], 0, 0, 0);
                aV[mf][nf] = __builtin_amdgcn_mfma_f32_16x16x32_bf16(fa[mf], fv[nf], aV[mf][nf], 0, 0, 0);
            }
    }
    #pragma unroll
    for (int nf = 0; nf < 2; nf++) {
        int col = o0 + w * 32 + nf * 16 + fr;
        float bks = bkb[col], bvs = bvb[col];
        #pragma unroll
        for (int mf = 0; mf < 4; mf++) {
            int row = i0 + mf * 16 + quad * 4;
            #pragma unroll
            for (int r = 0; r < 4; r++) {
                Kout[(size_t)(row + r) * D + col] = (bf16)(aK[mf][nf][r] + bks);
                Vout[(size_t)(row + r) * D + col] = (bf16)(aV[mf][nf][r] + bvs);
            }
        }
    }
}

// ---------------- kernel 5: attention + pooling, one WAVE per (graph, head) ----------------
// grid (2, NUM_GRAPHS), block 256 = 4 waves; wave w handles head blockIdx.x*4+w.
__global__ __launch_bounds__(256) void attn_kernel(const bf16* __restrict__ Kb,
                                                   const bf16* __restrict__ Vb,
                                                   const float* __restrict__ P2,
                                                   const float* __restrict__ bq,
                                                   const int* __restrict__ lb,
                                                   const int* __restrict__ udata,
                                                   float* __restrict__ pooled) {
    const int g = blockIdx.y;
    const int tid = threadIdx.x;
    const int lane = tid & 63;
    const int w = tid >> 6;
    const int h = blockIdx.x * 4 + w;
    const int off = lb[g];
    const int n = min(lb[g + 1] - off, MAX_N);

    __shared__ bf16 Qs[4][16 * QSTRIDE];   // 10 KB, wave-private slices
    __shared__ float wbar[4][MAX_N];       // 3 KB, wave-private slices
    __shared__ int upat_l[UMAX], ucnt_l[UMAX];

    const int* ubase = udata + (size_t)g * USTRIDE;
    const int nu = ubase[0];
    if (tid < 64) {
        upat_l[tid] = (tid < nu) ? ubase[1 + tid] : 0;
        ucnt_l[tid] = (tid < nu) ? ubase[65 + tid] : 0;
    }
    wbar[w][lane] = 0.f; wbar[w][64 + lane] = 0.f; wbar[w][128 + lane] = 0.f;
    __syncthreads();   // only block-wide sync; waves independent afterwards

    if (n == 0) { pooled[(size_t)g * D + h * 64 + lane] = 0.f; return; }

    const int fr = lane & 15;
    const int quad = lane >> 4;
    const float inv_n = 1.0f / (float)n;

    for (int c0 = 0; c0 < nu; c0 += 16) {
        // ---- build Q rows c0..c0+15 (bf16) in wave-private LDS ----
        {
            const int ul = lane >> 2;            // 0..15
            const int j0 = (lane & 3) * 16;      // 16 cols per lane
            const bool valid = (c0 + ul) < nu;   // c0+ul <= 63, in-bounds
            const int pat = upat_l[c0 + ul];
            const float* bp = bq + h * 64 + j0;
            float4 q0 = *(const float4*)bp;
            float4 q1 = *(const float4*)(bp + 4);
            float4 q2 = *(const float4*)(bp + 8);
            float4 q3 = *(const float4*)(bp + 12);
            #pragma unroll
            for (int p = 0; p < 8; p++) {
                const int hp = (pat >> (3 * p)) & 7;
                const float* pp = P2 + (size_t)(hp * 8 + p) * D + h * 64 + j0;
                float4 t0 = *(const float4*)pp;
                float4 t1 = *(const float4*)(pp + 4);
                float4 t2 = *(const float4*)(pp + 8);
                float4 t3 = *(const float4*)(pp + 12);
                q0.x += t0.x; q0.y += t0.y; q0.z += t0.z; q0.w += t0.w;
                q1.x += t1.x; q1.y += t1.y; q1.z += t1.z; q1.w += t1.w;
                q2.x += t2.x; q2.y += t2.y; q2.z += t2.z; q2.w += t2.w;
                q3.x += t3.x; q3.y += t3.y; q3.z += t3.z; q3.w += t3.w;
            }
            if (!valid) {
                q0.x=q0.y=q0.z=q0.w=0.f; q1.x=q1.y=q1.z=q1.w=0.f;
                q2.x=q2.y=q2.z=q2.w=0.f; q3.x=q3.y=q3.z=q3.w=0.f;
            }
            bf16x8 b0 = {(bf16)q0.x,(bf16)q0.y,(bf16)q0.z,(bf16)q0.w,
                         (bf16)q1.x,(bf16)q1.y,(bf16)q1.z,(bf16)q1.w};
            bf16x8 b1 = {(bf16)q2.x,(bf16)q2.y,(bf16)q2.z,(bf16)q2.w,
                         (bf16)q3.x,(bf16)q3.y,(bf16)q3.z,(bf16)q3.w};
            *(bf16x8*)(&Qs[w][ul * QSTRIDE + j0])     = b0;
            *(bf16x8*)(&Qs[w][ul * QSTRIDE + j0 + 8]) = b1;
        }
        // intra-wave LDS write->read: compiler-inserted lgkmcnt orders this (lockstep wave)
        bf16x8 fa0 = *(const bf16x8*)(&Qs[w][fr * QSTRIDE + quad * 8]);
        bf16x8 fa1 = *(const bf16x8*)(&Qs[w][fr * QSTRIDE + 32 + quad * 8]);

        // ---- scores: S[u=quad*4+r][s=st*16+fr], all 12 tiles in regs ----
        f32x4 sc[12];
        #pragma unroll
        for (int st = 0; st < 12; st++) {
            int s = st * 16 + fr;
            int row = off + (s < n ? s : n - 1);
            const bf16* kp = Kb + (size_t)row * D + h * 64 + quad * 8;
            bf16x8 fb0 = *(const bf16x8*)kp;
            bf16x8 fb1 = *(const bf16x8*)(kp + 32);
            f32x4 a = {0.f, 0.f, 0.f, 0.f};
            a = __builtin_amdgcn_mfma_f32_16x16x32_bf16(fa0, fb0, a, 0, 0, 0);
            a = __builtin_amdgcn_mfma_f32_16x16x32_bf16(fa1, fb1, a, 0, 0, 0);
            if (s < n) {
                sc[st].x = a.x * 0.125f; sc[st].y = a.y * 0.125f;
                sc[st].z = a.z * 0.125f; sc[st].w = a.w * 0.125f;
            } else {
                sc[st].x = sc[st].y = sc[st].z = sc[st].w = -1e30f;
            }
        }
        // ---- row max over s (within 16-lane quad groups) ----
        float m[4] = {-1e30f, -1e30f, -1e30f, -1e30f};
        #pragma unroll
        for (int st = 0; st < 12; st++) {
            m[0] = fmaxf(m[0], sc[st].x); m[1] = fmaxf(m[1], sc[st].y);
            m[2] = fmaxf(m[2], sc[st].z); m[3] = fmaxf(m[3], sc[st].w);
        }
        #pragma unroll
        for (int o = 1; o <= 8; o <<= 1) {
            #pragma unroll
            for (int r = 0; r < 4; r++) m[r] = fmaxf(m[r], __shfl_xor(m[r], o));
        }
        // ---- exp + row sums ----
        float den[4] = {0.f, 0.f, 0.f, 0.f};
        #pragma unroll
        for (int st = 0; st < 12; st++) {
            float e0 = __expf(sc[st].x - m[0]); float e1 = __expf(sc[st].y - m[1]);
            float e2 = __expf(sc[st].z - m[2]); float e3 = __expf(sc[st].w - m[3]);
            sc[st].x = e0; sc[st].y = e1; sc[st].z = e2; sc[st].w = e3;
            den[0] += e0; den[1] += e1; den[2] += e2; den[3] += e3;
        }
        #pragma unroll
        for (int o = 1; o <= 8; o <<= 1) {
            #pragma unroll
            for (int r = 0; r < 4; r++) den[r] += __shfl_xor(den[r], o);
        }
        float wf[4];
        #pragma unroll
        for (int r = 0; r < 4; r++)
            wf[r] = (float)ucnt_l[c0 + quad * 4 + r] * inv_n / den[r];
        // ---- accumulate column means into wbar ----
        #pragma unroll
        for (int st = 0; st < 12; st++) {
            float v = sc[st].x * wf[0] + sc[st].y * wf[1] + sc[st].z * wf[2] + sc[st].w * wf[3];
            v += __shfl_xor(v, 16);
            v += __shfl_xor(v, 32);
            if (lane < 16) wbar[w][st * 16 + lane] += v;
        }
    }

    // ---- V pass: pooled[g, h*64+j] = sum_s wbar[s] * V[off+s, h*64+j] ----
    float acc = 0.f;
    #pragma unroll 4
    for (int s = 0; s < n; s++)
        acc += wbar[w][s] * (float)Vb[(size_t)(off + s) * D + h * 64 + lane];
    pooled[(size_t)g * D + h * 64 + lane] = acc;
}

// ---------------- kernels 6/7: small projections ----------------
__global__ __launch_bounds__(256) void proj_o(const float* __restrict__ x_in,
                                              const float* __restrict__ W,
                                              const float* __restrict__ b,
                                              const int* __restrict__ lb,
                                              float* __restrict__ y) {
    const int g = blockIdx.x;
    __shared__ float xs[D];
    for (int d0 = threadIdx.x; d0 < D; d0 += 256) xs[d0] = x_in[(size_t)g * D + d0];
    __syncthreads();
    const int n = lb[g + 1] - lb[g];
    for (int o = threadIdx.x; o < D; o += 256) {
        const float* wr = W + (size_t)o * D;
        float acc = b[o];
        for (int d0 = 0; d0 < D; d0 += 4) {
            float4 wv = *(const float4*)(wr + d0);
            acc += xs[d0] * wv.x + xs[d0 + 1] * wv.y + xs[d0 + 2] * wv.z + xs[d0 + 3] * wv.w;
        }
        y[(size_t)g * D + o] = (n > 0) ? acc : 0.f;
    }
}

__global__ __launch_bounds__(256) void proj_p(const float* __restrict__ x_in,
                                              const float* __restrict__ W,
                                              const float* __restrict__ b,
                                              float* __restrict__ y) {
    const int g = blockIdx.x;
    __shared__ float xs[D];
    for (int d0 = threadIdx.x; d0 < D; d0 += 256) xs[d0] = x_in[(size_t)g * D + d0];
    __syncthreads();
    for (int o = threadIdx.x; o < D; o += 256) {
        const float* wr = W + (size_t)o * D;
        float acc = b[o];
        for (int d0 = 0; d0 < D; d0 += 4) {
            float4 wv = *(const float4*)(wr + d0);
            acc += xs[d0] * wv.x + xs[d0 + 1] * wv.y + xs[d0 + 2] * wv.z + xs[d0 + 3] * wv.w;
        }
        y[(size_t)g * D + o] = fmaxf(acc, 0.f);
    }
}

extern "C" void kernel_launch(void* const* d_in, const int* in_sizes, int n_in,
                              void* d_out, int out_size, void* d_ws, size_t ws_size,
                              hipStream_t stream) {
    const float* nf    = (const float*)d_in[0];
    const int*   batch = (const int*)d_in[1];
    const float* gq    = (const float*)d_in[2];
    const float* wq    = (const float*)d_in[3];
    const float* bq    = (const float*)d_in[4];
    const float* wk    = (const float*)d_in[5];
    const float* bk    = (const float*)d_in[6];
    const float* wv    = (const float*)d_in[7];
    const float* bv    = (const float*)d_in[8];
    const float* wo    = (const float*)d_in[9];
    const float* bo    = (const float*)d_in[10];
    const float* wp    = (const float*)d_in[11];
    const float* bp    = (const float*)d_in[12];
    float* out = (float*)d_out;

    // workspace layout (~131.3 MB total)
    char* ws = (char*)d_ws;
    bf16* Kbf = (bf16*)ws;                                     // 64 MiB
    bf16* Vbf = (bf16*)(ws + (size_t)N_NODES * D * 2);         // 64 MiB
    char* p = ws + (size_t)N_NODES * D * 4;
    int*  lb  = (int*)p;       p += 4096;
    bf16* Wkb = (bf16*)p;      p += (size_t)D * D * 2;
    bf16* Wvb = (bf16*)p;      p += (size_t)D * D * 2;
    float* P2 = (float*)p;     p += (size_t)64 * D * 4;
    float* pooled = (float*)p; p += (size_t)NUM_GRAPHS * D * 4;
    float* tmp = (float*)p;    p += (size_t)NUM_GRAPHS * D * 4;
    int* udata = (int*)tmp;    // aliases tmp: dedup writes -> attn reads -> proj_o overwrites

    lb_kernel<<<3, 256, 0, stream>>>(batch, lb);
    dedup_kernel<<<NUM_GRAPHS, 192, 0, stream>>>(lb, udata);
    cvt_kernel<<<(D * D / 4) / 256, 256, 0, stream>>>(wk, Wkb, D * D);
    cvt_kernel<<<(D * D / 4) / 256, 256, 0, stream>>>(wv, Wvb, D * D);
    p2_kernel<<<dim3(8, 8), 256, 0, stream>>>(gq, wq, P2);
    kv_gemm<<<dim3(N_NODES / 64, D / 128), 256, 0, stream>>>(nf, Wkb, Wvb, bk, bv, Kbf, Vbf);
    attn_kernel<<<dim3(2, NUM_GRAPHS), 256, 0, stream>>>(Kbf, Vbf, P2, bq, lb, udata, pooled);
    proj_o<<<NUM_GRAPHS, 256, 0, stream>>>(pooled, wo, bo, lb, tmp);
    proj_p<<<NUM_GRAPHS, 256, 0, stream>>>(tmp, wp, bp, out);
}

// Round 4
// 498.020 us; speedup vs baseline: 3.9686x; 1.1921x over previous
//
#include <hip/hip_runtime.h>
#include <hip/hip_bf16.h>
#include <cstdint>

typedef __bf16 bf16;
typedef __attribute__((ext_vector_type(8))) __bf16 bf16x8;
typedef __attribute__((ext_vector_type(4))) __bf16 bf16x4;
typedef __attribute__((ext_vector_type(4))) float f32x4;

#define N_NODES    65536
#define NUM_GRAPHS 512
#define MAX_N      192
#define D          512
#define H          8
#define DH         64
#define UMAX       64
#define USTRIDE    132
#define QSTRIDE    80
#define KV_LD      1024   // KV row stride (bf16 elems): cols 0..511 = K, 512..1023 = V

__device__ __forceinline__ void gload_lds16(const void* g, void* l) {
    __builtin_amdgcn_global_load_lds((const __attribute__((address_space(1))) void*)g,
                                     (__attribute__((address_space(3))) void*)l, 16, 0, 0);
}

// ---------------- kernel 1: graph boundaries ----------------
__global__ __launch_bounds__(256) void lb_kernel(const int* __restrict__ batch,
                                                 int* __restrict__ lb) {
    int g = blockIdx.x * 256 + threadIdx.x;
    if (g > NUM_GRAPHS) return;
    int lo = 0, hi = N_NODES;
    while (lo < hi) {
        int mid = (lo + hi) >> 1;
        if (batch[mid] < g) lo = mid + 1; else hi = mid;
    }
    lb[g] = lo;
}

// ---------------- kernel 1b: per-graph unique Q-row patterns ----------------
__global__ __launch_bounds__(192) void dedup_kernel(const int* __restrict__ lb,
                                                    int* __restrict__ udata) {
    const int g = blockIdx.x;
    const int off = lb[g];
    const int n = min(lb[g + 1] - off, MAX_N);
    __shared__ int keys[MAX_N];
    const int t = threadIdx.x;
    if (t < n) {
        unsigned un = (unsigned)n;
        int key = 0;
        #pragma unroll
        for (int p = 0; p < 8; p++) key |= (int)(((unsigned)(8 * t + p)) / un) << (3 * p);
        keys[t] = key;
    }
    __syncthreads();
    if (t == 0) {
        int* base = udata + (size_t)g * USTRIDE;
        int nu = 0;
        for (int s = 0; s < n; s++) {
            if (s == 0 || keys[s] != keys[s - 1]) {
                if (nu < UMAX) { base[1 + nu] = keys[s]; base[65 + nu] = 0; nu++; }
            }
            base[65 + (nu - 1)] += 1;
        }
        base[0] = nu;
    }
}

// ---------------- kernel 2: fp32 -> bf16 convert ----------------
__global__ __launch_bounds__(256) void cvt_kernel(const float* __restrict__ src,
                                                  bf16* __restrict__ dst, int n) {
    int i = (blockIdx.x * 256 + threadIdx.x) * 4;
    if (i >= n) return;
    float4 v = *(const float4*)(src + i);
    bf16x4 o = {(bf16)v.x, (bf16)v.y, (bf16)v.z, (bf16)v.w};
    *(bf16x4*)(dst + i) = o;
}

// ---------------- kernel 2b: stack biases ----------------
__global__ __launch_bounds__(256) void stack_bias(const float* __restrict__ bk,
                                                  const float* __restrict__ bv,
                                                  float* __restrict__ bkv) {
    int i = blockIdx.x * 256 + threadIdx.x;
    if (i < 512) bkv[i] = bk[i];
    else if (i < 1024) bkv[i] = bv[i - 512];
}

// ---------------- kernel 3: P2[h][p][o] = sum_j gq[h*64+j]*wq[o,64p+j] ----------------
__global__ __launch_bounds__(256) void p2_kernel(const float* __restrict__ gq,
                                                 const float* __restrict__ wq,
                                                 float* __restrict__ P2) {
    int h = blockIdx.x, p = blockIdx.y;
    __shared__ float gs[64];
    if (threadIdx.x < 64) gs[threadIdx.x] = gq[h * 64 + threadIdx.x];
    __syncthreads();
    for (int o = threadIdx.x; o < D; o += 256) {
        const float* wr = wq + (size_t)o * D + p * 64;
        float acc = 0.f;
        #pragma unroll 16
        for (int j = 0; j < 64; j++) acc += gs[j] * wr[j];
        P2[(size_t)(h * 8 + p) * D + o] = acc;
    }
}

// ---------------- kernel 4: KV GEMM, 128x128 tile, BK=32, global_load_lds for B ----------------
// KV[i, o] = sum_d A[i,d]*Wkv[o,d] + bkv[o], o in [0,1024). grid (8 N-tiles, 512 M-tiles).
__global__ __launch_bounds__(256) void kv_gemm(const float* __restrict__ A,
                                               const bf16* __restrict__ Wkv,
                                               const float* __restrict__ bkv,
                                               bf16* __restrict__ KV) {
    const int o0 = blockIdx.x * 128;
    const int i0 = blockIdx.y * 128;
    __shared__ bf16 As[128 * 32];   // 8 KB
    __shared__ bf16 Bs[128 * 32];   // 8 KB
    const int tid = threadIdx.x;
    const int lane = tid & 63;
    const int w = tid >> 6;
    const int wm = w & 1, wn = w >> 1;
    const int fr = lane & 15, quad = lane >> 4;
    const int ar = tid >> 1;            // A staging row 0..127
    const int ac = (tid & 1) * 16;      // A staging col 0/16
    const float* ap0 = A + (size_t)(i0 + ar) * D + ac;
    const bf16* bp0 = Wkv + (size_t)(o0 + w * 32 + (lane >> 2)) * D + (lane & 3) * 8;

    f32x4 acc[4][4] = {};

    for (int kt = 0; kt < D; kt += 32) {
        __syncthreads();
        // B tile via async global->LDS (wave-uniform base + lane*16)
        gload_lds16(bp0 + kt, Bs + (w * 32) * 32);
        gload_lds16(bp0 + (size_t)16 * D + kt, Bs + (w * 32 + 16) * 32);
        // A tile: fp32 -> bf16 through VGPRs
        {
            const float* ap = ap0 + kt;
            float4 x0 = *(const float4*)ap;
            float4 x1 = *(const float4*)(ap + 4);
            float4 x2 = *(const float4*)(ap + 8);
            float4 x3 = *(const float4*)(ap + 12);
            bf16x8 v0 = {(bf16)x0.x,(bf16)x0.y,(bf16)x0.z,(bf16)x0.w,
                         (bf16)x1.x,(bf16)x1.y,(bf16)x1.z,(bf16)x1.w};
            bf16x8 v1 = {(bf16)x2.x,(bf16)x2.y,(bf16)x2.z,(bf16)x2.w,
                         (bf16)x3.x,(bf16)x3.y,(bf16)x3.z,(bf16)x3.w};
            *(bf16x8*)(As + ar * 32 + ac) = v0;
            *(bf16x8*)(As + ar * 32 + ac + 8) = v1;
        }
        __syncthreads();
        bf16x8 fa[4], fb[4];
        #pragma unroll
        for (int mf = 0; mf < 4; mf++)
            fa[mf] = *(const bf16x8*)(As + (wm * 64 + mf * 16 + fr) * 32 + quad * 8);
        #pragma unroll
        for (int nf = 0; nf < 4; nf++)
            fb[nf] = *(const bf16x8*)(Bs + (wn * 64 + nf * 16 + fr) * 32 + quad * 8);
        #pragma unroll
        for (int mf = 0; mf < 4; mf++)
            #pragma unroll
            for (int nf = 0; nf < 4; nf++)
                acc[mf][nf] = __builtin_amdgcn_mfma_f32_16x16x32_bf16(fa[mf], fb[nf], acc[mf][nf], 0, 0, 0);
    }
    #pragma unroll
    for (int nf = 0; nf < 4; nf++) {
        const int col = o0 + wn * 64 + nf * 16 + fr;
        const float bs = bkv[col];
        #pragma unroll
        for (int mf = 0; mf < 4; mf++) {
            const int row = i0 + wm * 64 + mf * 16 + quad * 4;
            #pragma unroll
            for (int r = 0; r < 4; r++)
                KV[(size_t)(row + r) * KV_LD + col] = (bf16)(acc[mf][nf][r] + bs);
        }
    }
}

// ---------------- kernel 5: attention + pooling, one WAVE per (graph, head) ----------------
__global__ __launch_bounds__(256) void attn_kernel(const bf16* __restrict__ KV,
                                                   const float* __restrict__ P2,
                                                   const float* __restrict__ bq,
                                                   const int* __restrict__ lb,
                                                   const int* __restrict__ udata,
                                                   float* __restrict__ pooled) {
    const int g = blockIdx.y;
    const int tid = threadIdx.x;
    const int lane = tid & 63;
    const int w = tid >> 6;
    const int h = blockIdx.x * 4 + w;
    const int off = lb[g];
    const int n = min(lb[g + 1] - off, MAX_N);

    __shared__ bf16 Qs[4][16 * QSTRIDE];
    __shared__ float wbar[4][MAX_N];
    __shared__ int upat_l[UMAX], ucnt_l[UMAX];

    const int* ubase = udata + (size_t)g * USTRIDE;
    const int nu = ubase[0];
    if (tid < 64) {
        upat_l[tid] = (tid < nu) ? ubase[1 + tid] : 0;
        ucnt_l[tid] = (tid < nu) ? ubase[65 + tid] : 0;
    }
    wbar[w][lane] = 0.f; wbar[w][64 + lane] = 0.f; wbar[w][128 + lane] = 0.f;
    __syncthreads();

    if (n == 0) { pooled[(size_t)g * D + h * 64 + lane] = 0.f; return; }

    const int fr = lane & 15;
    const int quad = lane >> 4;
    const float inv_n = 1.0f / (float)n;

    for (int c0 = 0; c0 < nu; c0 += 16) {
        {   // build 16 Q rows (bf16) in wave-private LDS
            const int ul = lane >> 2;
            const int j0 = (lane & 3) * 16;
            const bool valid = (c0 + ul) < nu;
            const int pat = upat_l[c0 + ul];
            const float* bp = bq + h * 64 + j0;
            float4 q0 = *(const float4*)bp;
            float4 q1 = *(const float4*)(bp + 4);
            float4 q2 = *(const float4*)(bp + 8);
            float4 q3 = *(const float4*)(bp + 12);
            #pragma unroll
            for (int p = 0; p < 8; p++) {
                const int hp = (pat >> (3 * p)) & 7;
                const float* pp = P2 + (size_t)(hp * 8 + p) * D + h * 64 + j0;
                float4 t0 = *(const float4*)pp;
                float4 t1 = *(const float4*)(pp + 4);
                float4 t2 = *(const float4*)(pp + 8);
                float4 t3 = *(const float4*)(pp + 12);
                q0.x += t0.x; q0.y += t0.y; q0.z += t0.z; q0.w += t0.w;
                q1.x += t1.x; q1.y += t1.y; q1.z += t1.z; q1.w += t1.w;
                q2.x += t2.x; q2.y += t2.y; q2.z += t2.z; q2.w += t2.w;
                q3.x += t3.x; q3.y += t3.y; q3.z += t3.z; q3.w += t3.w;
            }
            if (!valid) {
                q0.x=q0.y=q0.z=q0.w=0.f; q1.x=q1.y=q1.z=q1.w=0.f;
                q2.x=q2.y=q2.z=q2.w=0.f; q3.x=q3.y=q3.z=q3.w=0.f;
            }
            bf16x8 b0 = {(bf16)q0.x,(bf16)q0.y,(bf16)q0.z,(bf16)q0.w,
                         (bf16)q1.x,(bf16)q1.y,(bf16)q1.z,(bf16)q1.w};
            bf16x8 b1 = {(bf16)q2.x,(bf16)q2.y,(bf16)q2.z,(bf16)q2.w,
                         (bf16)q3.x,(bf16)q3.y,(bf16)q3.z,(bf16)q3.w};
            *(bf16x8*)(&Qs[w][ul * QSTRIDE + j0])     = b0;
            *(bf16x8*)(&Qs[w][ul * QSTRIDE + j0 + 8]) = b1;
        }
        bf16x8 fa0 = *(const bf16x8*)(&Qs[w][fr * QSTRIDE + quad * 8]);
        bf16x8 fa1 = *(const bf16x8*)(&Qs[w][fr * QSTRIDE + 32 + quad * 8]);

        f32x4 sc[12];
        #pragma unroll
        for (int st = 0; st < 12; st++) {
            if (st * 16 < n) {
                int s = st * 16 + fr;
                int row = off + (s < n ? s : n - 1);
                const bf16* kp = KV + (size_t)row * KV_LD + h * 64 + quad * 8;
                bf16x8 fb0 = *(const bf16x8*)kp;
                bf16x8 fb1 = *(const bf16x8*)(kp + 32);
                f32x4 a = {0.f, 0.f, 0.f, 0.f};
                a = __builtin_amdgcn_mfma_f32_16x16x32_bf16(fa0, fb0, a, 0, 0, 0);
                a = __builtin_amdgcn_mfma_f32_16x16x32_bf16(fa1, fb1, a, 0, 0, 0);
                if (s < n) {
                    sc[st].x = a.x * 0.125f; sc[st].y = a.y * 0.125f;
                    sc[st].z = a.z * 0.125f; sc[st].w = a.w * 0.125f;
                } else {
                    sc[st].x = sc[st].y = sc[st].z = sc[st].w = -1e30f;
                }
            } else {
                sc[st].x = sc[st].y = sc[st].z = sc[st].w = -1e30f;
            }
        }
        float m[4] = {-1e30f, -1e30f, -1e30f, -1e30f};
        #pragma unroll
        for (int st = 0; st < 12; st++) {
            m[0] = fmaxf(m[0], sc[st].x); m[1] = fmaxf(m[1], sc[st].y);
            m[2] = fmaxf(m[2], sc[st].z); m[3] = fmaxf(m[3], sc[st].w);
        }
        #pragma unroll
        for (int o = 1; o <= 8; o <<= 1) {
            #pragma unroll
            for (int r = 0; r < 4; r++) m[r] = fmaxf(m[r], __shfl_xor(m[r], o));
        }
        float den[4] = {0.f, 0.f, 0.f, 0.f};
        #pragma unroll
        for (int st = 0; st < 12; st++) {
            float e0 = __expf(sc[st].x - m[0]); float e1 = __expf(sc[st].y - m[1]);
            float e2 = __expf(sc[st].z - m[2]); float e3 = __expf(sc[st].w - m[3]);
            sc[st].x = e0; sc[st].y = e1; sc[st].z = e2; sc[st].w = e3;
            den[0] += e0; den[1] += e1; den[2] += e2; den[3] += e3;
        }
        #pragma unroll
        for (int o = 1; o <= 8; o <<= 1) {
            #pragma unroll
            for (int r = 0; r < 4; r++) den[r] += __shfl_xor(den[r], o);
        }
        float wf[4];
        #pragma unroll
        for (int r = 0; r < 4; r++)
            wf[r] = (float)ucnt_l[c0 + quad * 4 + r] * inv_n / den[r];
        #pragma unroll
        for (int st = 0; st < 12; st++) {
            float v = sc[st].x * wf[0] + sc[st].y * wf[1] + sc[st].z * wf[2] + sc[st].w * wf[3];
            v += __shfl_xor(v, 16);
            v += __shfl_xor(v, 32);
            if (lane < 16) wbar[w][st * 16 + lane] += v;
        }
    }

    // V pass: 4 s-rows per iteration, bf16x4 per lane
    {
        const int jv = (lane & 15) * 4;
        const int sb = lane >> 4;
        float4 va = {0.f, 0.f, 0.f, 0.f};
        const bf16* vb = KV + 512 + h * 64 + jv;
        for (int s = sb; s < n; s += 4) {
            float wv = wbar[w][s];
            bf16x4 v4 = *(const bf16x4*)(vb + (size_t)(off + s) * KV_LD);
            va.x += wv * (float)v4[0]; va.y += wv * (float)v4[1];
            va.z += wv * (float)v4[2]; va.w += wv * (float)v4[3];
        }
        va.x += __shfl_xor(va.x, 16); va.y += __shfl_xor(va.y, 16);
        va.z += __shfl_xor(va.z, 16); va.w += __shfl_xor(va.w, 16);
        va.x += __shfl_xor(va.x, 32); va.y += __shfl_xor(va.y, 32);
        va.z += __shfl_xor(va.z, 32); va.w += __shfl_xor(va.w, 32);
        if (lane < 16) *(float4*)(pooled + (size_t)g * D + h * 64 + jv) = va;
    }
}

// ---------------- kernel 6: projection GEMM (512x512x512), MFMA ----------------
// Y[i,o] = A[i,:] . Wb[o,:] + bias[o]; mode 0: zero rows with n==0 (lb); mode 1: relu.
__global__ __launch_bounds__(256) void proj_gemm(const float* __restrict__ A,
                                                 const bf16* __restrict__ Wb,
                                                 const float* __restrict__ bias,
                                                 const int* __restrict__ lb,
                                                 int mode,
                                                 float* __restrict__ Y) {
    const int o0 = blockIdx.x * 128;
    const int i0 = blockIdx.y * 128;
    __shared__ bf16 As[128 * 32];
    __shared__ bf16 Bs[128 * 32];
    const int tid = threadIdx.x;
    const int lane = tid & 63;
    const int w = tid >> 6;
    const int wm = w & 1, wn = w >> 1;
    const int fr = lane & 15, quad = lane >> 4;
    const int ar = tid >> 1;
    const int ac = (tid & 1) * 16;
    const float* ap0 = A + (size_t)(i0 + ar) * D + ac;
    const bf16* bp0 = Wb + (size_t)(o0 + w * 32 + (lane >> 2)) * D + (lane & 3) * 8;

    f32x4 acc[4][4] = {};

    for (int kt = 0; kt < D; kt += 32) {
        __syncthreads();
        gload_lds16(bp0 + kt, Bs + (w * 32) * 32);
        gload_lds16(bp0 + (size_t)16 * D + kt, Bs + (w * 32 + 16) * 32);
        {
            const float* ap = ap0 + kt;
            float4 x0 = *(const float4*)ap;
            float4 x1 = *(const float4*)(ap + 4);
            float4 x2 = *(const float4*)(ap + 8);
            float4 x3 = *(const float4*)(ap + 12);
            bf16x8 v0 = {(bf16)x0.x,(bf16)x0.y,(bf16)x0.z,(bf16)x0.w,
                         (bf16)x1.x,(bf16)x1.y,(bf16)x1.z,(bf16)x1.w};
            bf16x8 v1 = {(bf16)x2.x,(bf16)x2.y,(bf16)x2.z,(bf16)x2.w,
                         (bf16)x3.x,(bf16)x3.y,(bf16)x3.z,(bf16)x3.w};
            *(bf16x8*)(As + ar * 32 + ac) = v0;
            *(bf16x8*)(As + ar * 32 + ac + 8) = v1;
        }
        __syncthreads();
        bf16x8 fa[4], fb[4];
        #pragma unroll
        for (int mf = 0; mf < 4; mf++)
            fa[mf] = *(const bf16x8*)(As + (wm * 64 + mf * 16 + fr) * 32 + quad * 8);
        #pragma unroll
        for (int nf = 0; nf < 4; nf++)
            fb[nf] = *(const bf16x8*)(Bs + (wn * 64 + nf * 16 + fr) * 32 + quad * 8);
        #pragma unroll
        for (int mf = 0; mf < 4; mf++)
            #pragma unroll
            for (int nf = 0; nf < 4; nf++)
                acc[mf][nf] = __builtin_amdgcn_mfma_f32_16x16x32_bf16(fa[mf], fb[nf], acc[mf][nf], 0, 0, 0);
    }
    #pragma unroll
    for (int nf = 0; nf < 4; nf++) {
        const int col = o0 + wn * 64 + nf * 16 + fr;
        const float bs = bias[col];
        #pragma unroll
        for (int mf = 0; mf < 4; mf++) {
            const int row = i0 + wm * 64 + mf * 16 + quad * 4;
            #pragma unroll
            for (int r = 0; r < 4; r++) {
                float val = acc[mf][nf][r] + bs;
                if (mode == 0) {
                    int gg = row + r;
                    if (lb[gg + 1] - lb[gg] <= 0) val = 0.f;
                } else {
                    val = fmaxf(val, 0.f);
                }
                Y[(size_t)(row + r) * D + col] = val;
            }
        }
    }
}

extern "C" void kernel_launch(void* const* d_in, const int* in_sizes, int n_in,
                              void* d_out, int out_size, void* d_ws, size_t ws_size,
                              hipStream_t stream) {
    const float* nf    = (const float*)d_in[0];
    const int*   batch = (const int*)d_in[1];
    const float* gq    = (const float*)d_in[2];
    const float* wq    = (const float*)d_in[3];
    const float* bq    = (const float*)d_in[4];
    const float* wk    = (const float*)d_in[5];
    const float* bk    = (const float*)d_in[6];
    const float* wv    = (const float*)d_in[7];
    const float* bv    = (const float*)d_in[8];
    const float* wo    = (const float*)d_in[9];
    const float* bo    = (const float*)d_in[10];
    const float* wp    = (const float*)d_in[11];
    const float* bp    = (const float*)d_in[12];
    float* out = (float*)d_out;

    // workspace layout (~132.3 MB)
    char* ws = (char*)d_ws;
    bf16* KV = (bf16*)ws;                                      // 128 MiB, row stride 1024
    char* p = ws + (size_t)N_NODES * KV_LD * 2;
    int*  lb   = (int*)p;      p += 4096;
    bf16* Wkvb = (bf16*)p;     p += (size_t)1024 * D * 2;      // 1 MiB (Wk rows 0..511, Wv 512..1023)
    float* bkv = (float*)p;    p += 4096;
    bf16* Wob  = (bf16*)p;     p += (size_t)D * D * 2;         // 512 KiB
    bf16* Wpb  = (bf16*)p;     p += (size_t)D * D * 2;         // 512 KiB
    float* P2  = (float*)p;    p += (size_t)64 * D * 4;        // 128 KiB
    float* pooled = (float*)p; p += (size_t)NUM_GRAPHS * D * 4;// 1 MiB
    float* tmp = (float*)p;    p += (size_t)NUM_GRAPHS * D * 4;// 1 MiB
    int* udata = (int*)tmp;    // aliases tmp: dedup -> attn reads -> proj_o overwrites tmp after

    lb_kernel<<<3, 256, 0, stream>>>(batch, lb);
    dedup_kernel<<<NUM_GRAPHS, 192, 0, stream>>>(lb, udata);
    cvt_kernel<<<(D * D / 4) / 256, 256, 0, stream>>>(wk, Wkvb, D * D);
    cvt_kernel<<<(D * D / 4) / 256, 256, 0, stream>>>(wv, Wkvb + (size_t)512 * D, D * D);
    cvt_kernel<<<(D * D / 4) / 256, 256, 0, stream>>>(wo, Wob, D * D);
    cvt_kernel<<<(D * D / 4) / 256, 256, 0, stream>>>(wp, Wpb, D * D);
    stack_bias<<<4, 256, 0, stream>>>(bk, bv, bkv);
    p2_kernel<<<dim3(8, 8), 256, 0, stream>>>(gq, wq, P2);
    kv_gemm<<<dim3(8, N_NODES / 128), 256, 0, stream>>>(nf, Wkvb, bkv, KV);
    attn_kernel<<<dim3(2, NUM_GRAPHS), 256, 0, stream>>>(KV, P2, bq, lb, udata, pooled);
    proj_gemm<<<dim3(4, 4), 256, 0, stream>>>(pooled, Wob, bo, lb, 0, tmp);
    proj_gemm<<<dim3(4, 4), 256, 0, stream>>>(tmp, Wpb, bp, lb, 1, out);
}

// Round 5
// 446.396 us; speedup vs baseline: 4.4276x; 1.1156x over previous
//
#include <hip/hip_runtime.h>
#include <hip/hip_bf16.h>
#include <cstdint>

typedef __bf16 bf16;
typedef __attribute__((ext_vector_type(8))) __bf16 bf16x8;
typedef __attribute__((ext_vector_type(4))) __bf16 bf16x4;
typedef __attribute__((ext_vector_type(2))) __bf16 bf16x2;
typedef __attribute__((ext_vector_type(4))) float f32x4;

#define N_NODES    65536
#define NUM_GRAPHS 512
#define MAX_N      192
#define D          512
#define H          8
#define DH         64
#define UMAX       64
#define USTRIDE    132

__device__ __forceinline__ void gload_lds16(const void* g, void* l) {
    __builtin_amdgcn_global_load_lds((const __attribute__((address_space(1))) void*)g,
                                     (__attribute__((address_space(3))) void*)l, 16, 0, 0);
}

// ---------------- kernel: graph boundaries ----------------
__global__ __launch_bounds__(256) void lb_kernel(const int* __restrict__ batch,
                                                 int* __restrict__ lb) {
    int g = blockIdx.x * 256 + threadIdx.x;
    if (g > NUM_GRAPHS) return;
    int lo = 0, hi = N_NODES;
    while (lo < hi) {
        int mid = (lo + hi) >> 1;
        if (batch[mid] < g) lo = mid + 1; else hi = mid;
    }
    lb[g] = lo;
}

// ---------------- kernel: per-graph unique Q-row patterns ----------------
__global__ __launch_bounds__(192) void dedup_kernel(const int* __restrict__ lb,
                                                    int* __restrict__ udata) {
    const int g = blockIdx.x;
    const int off = lb[g];
    const int n = min(lb[g + 1] - off, MAX_N);
    __shared__ int keys[MAX_N];
    const int t = threadIdx.x;
    if (t < n) {
        unsigned un = (unsigned)n;
        int key = 0;
        #pragma unroll
        for (int p = 0; p < 8; p++) key |= (int)(((unsigned)(8 * t + p)) / un) << (3 * p);
        keys[t] = key;
    }
    __syncthreads();
    if (t == 0) {
        int* base = udata + (size_t)g * USTRIDE;
        int nu = 0;
        for (int s = 0; s < n; s++) {
            if (s == 0 || keys[s] != keys[s - 1]) {
                if (nu < UMAX) { base[1 + nu] = keys[s]; base[65 + nu] = 0; nu++; }
            }
            base[65 + (nu - 1)] += 1;
        }
        base[0] = nu;
    }
}

// ---------------- kernel: fp32 -> bf16 convert ----------------
__global__ __launch_bounds__(256) void cvt_kernel(const float* __restrict__ src,
                                                  bf16* __restrict__ dst, int n) {
    int i = (blockIdx.x * 256 + threadIdx.x) * 4;
    if (i >= n) return;
    float4 v = *(const float4*)(src + i);
    bf16x4 o = {(bf16)v.x, (bf16)v.y, (bf16)v.z, (bf16)v.w};
    *(bf16x4*)(dst + i) = o;
}

// ---------------- kernel: P2[h][p][o] = sum_j gq[h*64+j]*wq[o,64p+j] ----------------
__global__ __launch_bounds__(256) void p2_kernel(const float* __restrict__ gq,
                                                 const float* __restrict__ wq,
                                                 float* __restrict__ P2) {
    int h = blockIdx.x, p = blockIdx.y;
    __shared__ float gs[64];
    if (threadIdx.x < 64) gs[threadIdx.x] = gq[h * 64 + threadIdx.x];
    __syncthreads();
    for (int o = threadIdx.x; o < D; o += 256) {
        const float* wr = wq + (size_t)o * D + p * 64;
        float acc = 0.f;
        #pragma unroll 16
        for (int j = 0; j < 64; j++) acc += gs[j] * wr[j];
        P2[(size_t)(h * 8 + p) * D + o] = acc;
    }
}

// ---------------- kernel: Wov[o, h*512+d'] = sum_j wo[o,h*64+j]*wv[h*64+j,d'] ----------------
__global__ __launch_bounds__(256) void wov_kernel(const float* __restrict__ wo,
                                                  const float* __restrict__ wv,
                                                  bf16* __restrict__ Wov) {
    const int ot = blockIdx.x;   // o block of 32
    const int h  = blockIdx.y;
    __shared__ float wos[32 * 64];
    for (int idx = threadIdx.x; idx < 32 * 64; idx += 256) {
        int ol = idx >> 6, j = idx & 63;
        wos[idx] = wo[(size_t)(ot * 32 + ol) * D + h * 64 + j];
    }
    __syncthreads();
    const int c = threadIdx.x * 2;
    float acc0[32] = {}, acc1[32] = {};
    for (int j = 0; j < 64; j++) {
        float2 v2 = *(const float2*)(wv + (size_t)(h * 64 + j) * D + c);
        #pragma unroll
        for (int o = 0; o < 32; o++) {
            float wj = wos[o * 64 + j];
            acc0[o] += wj * v2.x; acc1[o] += wj * v2.y;
        }
    }
    #pragma unroll
    for (int o = 0; o < 32; o++) {
        bf16x2 r = {(bf16)acc0[o], (bf16)acc1[o]};
        *(bf16x2*)(Wov + (size_t)(ot * 32 + o) * 4096 + h * 512 + c) = r;
    }
}

// ---------------- kernel: cst[o] = wo[o,:].bv + bo[o] ----------------
__global__ __launch_bounds__(256) void cst_kernel(const float* __restrict__ wo,
                                                  const float* __restrict__ bv,
                                                  const float* __restrict__ bo,
                                                  float* __restrict__ cst) {
    int o = blockIdx.x * 256 + threadIdx.x;
    if (o >= D) return;
    const float* wr = wo + (size_t)o * D;
    float acc = bo[o];
    for (int d0 = 0; d0 < D; d0 += 4) {
        float4 wv4 = *(const float4*)(wr + d0);
        float4 b4  = *(const float4*)(bv + d0);
        acc += wv4.x * b4.x + wv4.y * b4.y + wv4.z * b4.z + wv4.w * b4.w;
    }
    cst[o] = acc;
}

// ---------------- kernel: K GEMM, 128x128 tile, both operands via global_load_lds ----------------
// K[i,o] = sum_d Ab[i,d]*Wkb[o,d] + bk[o]. grid (512 m-strips fast, 4 n-tiles slow).
__global__ __launch_bounds__(256) void k_gemm(const bf16* __restrict__ Ab,
                                              const bf16* __restrict__ Wkb,
                                              const float* __restrict__ bkb,
                                              bf16* __restrict__ Kout) {
    const int i0 = blockIdx.x * 128;
    const int o0 = blockIdx.y * 128;
    __shared__ bf16 As[128 * 32];
    __shared__ bf16 Bs[128 * 32];
    const int tid = threadIdx.x;
    const int lane = tid & 63;
    const int w = tid >> 6;
    const int wm = w & 1, wn = w >> 1;
    const int fr = lane & 15, quad = lane >> 4;
    const bf16* gA = Ab + (size_t)(i0 + w * 32 + (lane >> 2)) * D + (lane & 3) * 8;
    const bf16* gB = Wkb + (size_t)(o0 + w * 32 + (lane >> 2)) * D + (lane & 3) * 8;
    bf16* lA = As + (w * 32) * 32;
    bf16* lB = Bs + (w * 32) * 32;

    f32x4 acc[4][4] = {};

    for (int kt = 0; kt < D; kt += 32) {
        __syncthreads();
        gload_lds16(gA + kt, lA);
        gload_lds16(gA + (size_t)16 * D + kt, lA + 16 * 32);
        gload_lds16(gB + kt, lB);
        gload_lds16(gB + (size_t)16 * D + kt, lB + 16 * 32);
        __syncthreads();
        bf16x8 fa[4], fb[4];
        #pragma unroll
        for (int mf = 0; mf < 4; mf++)
            fa[mf] = *(const bf16x8*)(As + (wm * 64 + mf * 16 + fr) * 32 + quad * 8);
        #pragma unroll
        for (int nf = 0; nf < 4; nf++)
            fb[nf] = *(const bf16x8*)(Bs + (wn * 64 + nf * 16 + fr) * 32 + quad * 8);
        #pragma unroll
        for (int mf = 0; mf < 4; mf++)
            #pragma unroll
            for (int nf = 0; nf < 4; nf++)
                acc[mf][nf] = __builtin_amdgcn_mfma_f32_16x16x32_bf16(fa[mf], fb[nf], acc[mf][nf], 0, 0, 0);
    }
    #pragma unroll
    for (int nf = 0; nf < 4; nf++) {
        const int col = o0 + wn * 64 + nf * 16 + fr;
        const float bs = bkb[col];
        #pragma unroll
        for (int mf = 0; mf < 4; mf++) {
            const int row = i0 + wm * 64 + mf * 16 + quad * 4;
            #pragma unroll
            for (int r = 0; r < 4; r++)
                Kout[(size_t)(row + r) * D + col] = (bf16)(acc[mf][nf][r] + bs);
        }
    }
}

// ---------------- kernel: attention -> mean attn weights Wbar[h][node] ----------------
// one WAVE per (graph, head); grid (2, NUM_GRAPHS), 4 waves/block.
__global__ __launch_bounds__(256) void attn_kernel(const bf16* __restrict__ Kb,
                                                   const float* __restrict__ P2,
                                                   const float* __restrict__ bq,
                                                   const int* __restrict__ lb,
                                                   const int* __restrict__ udata,
                                                   float* __restrict__ Wbar) {
    const int g = blockIdx.y;
    const int tid = threadIdx.x;
    const int lane = tid & 63;
    const int w = tid >> 6;
    const int h = blockIdx.x * 4 + w;
    const int off = lb[g];
    const int n = min(lb[g + 1] - off, MAX_N);

    __shared__ bf16 Qs[4][16 * 80];
    __shared__ float wacc[4][MAX_N];
    __shared__ int upat_l[UMAX], ucnt_l[UMAX];

    const int* ubase = udata + (size_t)g * USTRIDE;
    const int nu = ubase[0];
    if (tid < 64) {
        upat_l[tid] = (tid < nu) ? ubase[1 + tid] : 0;
        ucnt_l[tid] = (tid < nu) ? ubase[65 + tid] : 0;
    }
    wacc[w][lane] = 0.f; wacc[w][64 + lane] = 0.f; wacc[w][128 + lane] = 0.f;
    __syncthreads();

    if (n == 0) return;

    const int fr = lane & 15;
    const int quad = lane >> 4;
    const float inv_n = 1.0f / (float)n;

    for (int c0 = 0; c0 < nu; c0 += 16) {
        {   // build 16 Q rows (bf16) in wave-private LDS
            const int ul = lane >> 2;
            const int j0 = (lane & 3) * 16;
            const bool valid = (c0 + ul) < nu;
            const int pat = upat_l[c0 + ul];
            const float* bpq = bq + h * 64 + j0;
            float4 q0 = *(const float4*)bpq;
            float4 q1 = *(const float4*)(bpq + 4);
            float4 q2 = *(const float4*)(bpq + 8);
            float4 q3 = *(const float4*)(bpq + 12);
            #pragma unroll
            for (int p = 0; p < 8; p++) {
                const int hp = (pat >> (3 * p)) & 7;
                const float* pp = P2 + (size_t)(hp * 8 + p) * D + h * 64 + j0;
                float4 t0 = *(const float4*)pp;
                float4 t1 = *(const float4*)(pp + 4);
                float4 t2 = *(const float4*)(pp + 8);
                float4 t3 = *(const float4*)(pp + 12);
                q0.x += t0.x; q0.y += t0.y; q0.z += t0.z; q0.w += t0.w;
                q1.x += t1.x; q1.y += t1.y; q1.z += t1.z; q1.w += t1.w;
                q2.x += t2.x; q2.y += t2.y; q2.z += t2.z; q2.w += t2.w;
                q3.x += t3.x; q3.y += t3.y; q3.z += t3.z; q3.w += t3.w;
            }
            if (!valid) {
                q0.x=q0.y=q0.z=q0.w=0.f; q1.x=q1.y=q1.z=q1.w=0.f;
                q2.x=q2.y=q2.z=q2.w=0.f; q3.x=q3.y=q3.z=q3.w=0.f;
            }
            bf16x8 b0 = {(bf16)q0.x,(bf16)q0.y,(bf16)q0.z,(bf16)q0.w,
                         (bf16)q1.x,(bf16)q1.y,(bf16)q1.z,(bf16)q1.w};
            bf16x8 b1 = {(bf16)q2.x,(bf16)q2.y,(bf16)q2.z,(bf16)q2.w,
                         (bf16)q3.x,(bf16)q3.y,(bf16)q3.z,(bf16)q3.w};
            *(bf16x8*)(&Qs[w][ul * 80 + j0])     = b0;
            *(bf16x8*)(&Qs[w][ul * 80 + j0 + 8]) = b1;
        }
        bf16x8 fa0 = *(const bf16x8*)(&Qs[w][fr * 80 + quad * 8]);
        bf16x8 fa1 = *(const bf16x8*)(&Qs[w][fr * 80 + 32 + quad * 8]);

        f32x4 sc[12];
        #pragma unroll
        for (int st = 0; st < 12; st++) {
            if (st * 16 < n) {
                int s = st * 16 + fr;
                int row = off + (s < n ? s : n - 1);
                const bf16* kp = Kb + (size_t)row * D + h * 64 + quad * 8;
                bf16x8 fb0 = *(const bf16x8*)kp;
                bf16x8 fb1 = *(const bf16x8*)(kp + 32);
                f32x4 a = {0.f, 0.f, 0.f, 0.f};
                a = __builtin_amdgcn_mfma_f32_16x16x32_bf16(fa0, fb0, a, 0, 0, 0);
                a = __builtin_amdgcn_mfma_f32_16x16x32_bf16(fa1, fb1, a, 0, 0, 0);
                if (s < n) {
                    sc[st].x = a.x * 0.125f; sc[st].y = a.y * 0.125f;
                    sc[st].z = a.z * 0.125f; sc[st].w = a.w * 0.125f;
                } else {
                    sc[st].x = sc[st].y = sc[st].z = sc[st].w = -1e30f;
                }
            } else {
                sc[st].x = sc[st].y = sc[st].z = sc[st].w = -1e30f;
            }
        }
        float m[4] = {-1e30f, -1e30f, -1e30f, -1e30f};
        #pragma unroll
        for (int st = 0; st < 12; st++) {
            m[0] = fmaxf(m[0], sc[st].x); m[1] = fmaxf(m[1], sc[st].y);
            m[2] = fmaxf(m[2], sc[st].z); m[3] = fmaxf(m[3], sc[st].w);
        }
        #pragma unroll
        for (int o = 1; o <= 8; o <<= 1) {
            #pragma unroll
            for (int r = 0; r < 4; r++) m[r] = fmaxf(m[r], __shfl_xor(m[r], o));
        }
        float den[4] = {0.f, 0.f, 0.f, 0.f};
        #pragma unroll
        for (int st = 0; st < 12; st++) {
            float e0 = __expf(sc[st].x - m[0]); float e1 = __expf(sc[st].y - m[1]);
            float e2 = __expf(sc[st].z - m[2]); float e3 = __expf(sc[st].w - m[3]);
            sc[st].x = e0; sc[st].y = e1; sc[st].z = e2; sc[st].w = e3;
            den[0] += e0; den[1] += e1; den[2] += e2; den[3] += e3;
        }
        #pragma unroll
        for (int o = 1; o <= 8; o <<= 1) {
            #pragma unroll
            for (int r = 0; r < 4; r++) den[r] += __shfl_xor(den[r], o);
        }
        float wf[4];
        #pragma unroll
        for (int r = 0; r < 4; r++)
            wf[r] = (float)ucnt_l[c0 + quad * 4 + r] * inv_n / den[r];
        #pragma unroll
        for (int st = 0; st < 12; st++) {
            float v = sc[st].x * wf[0] + sc[st].y * wf[1] + sc[st].z * wf[2] + sc[st].w * wf[3];
            v += __shfl_xor(v, 16);
            v += __shfl_xor(v, 32);
            if (lane < 16) wacc[w][st * 16 + lane] += v;
        }
    }
    // write mean weights for this (g,h): plane layout [h][node]
    for (int s = lane; s < n; s += 64)
        Wbar[(size_t)h * N_NODES + off + s] = wacc[w][s];
}

// ---------------- kernel: abar[g, h*512+d'] = sum_s Wbar[h][off+s] * A[off+s, d'] ----------------
__global__ __launch_bounds__(256) void abar_kernel(const float* __restrict__ A,
                                                   const float* __restrict__ Wbar,
                                                   const int* __restrict__ lb,
                                                   bf16* __restrict__ abar) {
    const int g = blockIdx.x;
    const int off = lb[g];
    const int n = min(lb[g + 1] - off, MAX_N);
    const int tid = threadIdx.x;
    bf16* outg = abar + (size_t)g * 4096;
    if (n == 0) {
        bf16x2 z = {(bf16)0.f, (bf16)0.f};
        for (int idx = tid; idx < 2048; idx += 256) *(bf16x2*)(outg + idx * 2) = z;
        return;
    }
    __shared__ float wsh[MAX_N * 8];
    for (int idx = tid; idx < n * 8; idx += 256) {
        int s = idx >> 3, h = idx & 7;
        wsh[idx] = Wbar[(size_t)h * N_NODES + off + s];
    }
    __syncthreads();
    const int c = tid * 2;
    float acc0[8] = {}, acc1[8] = {};
    for (int s = 0; s < n; s++) {
        float2 a2 = *(const float2*)(A + (size_t)(off + s) * D + c);
        const float* wp_ = wsh + s * 8;
        #pragma unroll
        for (int h = 0; h < 8; h++) {
            acc0[h] += wp_[h] * a2.x;
            acc1[h] += wp_[h] * a2.y;
        }
    }
    #pragma unroll
    for (int h = 0; h < 8; h++) {
        bf16x2 r = {(bf16)acc0[h], (bf16)acc1[h]};
        *(bf16x2*)(outg + h * 512 + c) = r;
    }
}

// ---------------- kernel: zero tmp ----------------
__global__ __launch_bounds__(256) void zero_kernel(float* __restrict__ p, int n4) {
    int i = blockIdx.x * 256 + threadIdx.x;
    if (i < n4) { float4 z = {0.f, 0.f, 0.f, 0.f}; *(float4*)(p + i * 4) = z; }
}

// ---------------- kernel: fused Wov GEMM, M=512 N=512 K=4096, split-K atomics ----------------
__global__ __launch_bounds__(256) void og_gemm(const bf16* __restrict__ Ab,
                                               const bf16* __restrict__ Bb,
                                               float* __restrict__ Yt) {
    const int o0 = blockIdx.x * 128;
    const int i0 = blockIdx.y * 128;
    const int k0 = blockIdx.z * 512;
    __shared__ bf16 As[128 * 32];
    __shared__ bf16 Bs[128 * 32];
    const int tid = threadIdx.x;
    const int lane = tid & 63;
    const int w = tid >> 6;
    const int wm = w & 1, wn = w >> 1;
    const int fr = lane & 15, quad = lane >> 4;
    const bf16* gA = Ab + (size_t)(i0 + w * 32 + (lane >> 2)) * 4096 + k0 + (lane & 3) * 8;
    const bf16* gB = Bb + (size_t)(o0 + w * 32 + (lane >> 2)) * 4096 + k0 + (lane & 3) * 8;
    bf16* lA = As + (w * 32) * 32;
    bf16* lB = Bs + (w * 32) * 32;

    f32x4 acc[4][4] = {};

    for (int kt = 0; kt < 512; kt += 32) {
        __syncthreads();
        gload_lds16(gA + kt, lA);
        gload_lds16(gA + (size_t)16 * 4096 + kt, lA + 16 * 32);
        gload_lds16(gB + kt, lB);
        gload_lds16(gB + (size_t)16 * 4096 + kt, lB + 16 * 32);
        __syncthreads();
        bf16x8 fa[4], fb[4];
        #pragma unroll
        for (int mf = 0; mf < 4; mf++)
            fa[mf] = *(const bf16x8*)(As + (wm * 64 + mf * 16 + fr) * 32 + quad * 8);
        #pragma unroll
        for (int nf = 0; nf < 4; nf++)
            fb[nf] = *(const bf16x8*)(Bs + (wn * 64 + nf * 16 + fr) * 32 + quad * 8);
        #pragma unroll
        for (int mf = 0; mf < 4; mf++)
            #pragma unroll
            for (int nf = 0; nf < 4; nf++)
                acc[mf][nf] = __builtin_amdgcn_mfma_f32_16x16x32_bf16(fa[mf], fb[nf], acc[mf][nf], 0, 0, 0);
    }
    #pragma unroll
    for (int nf = 0; nf < 4; nf++) {
        const int col = o0 + wn * 64 + nf * 16 + fr;
        #pragma unroll
        for (int mf = 0; mf < 4; mf++) {
            const int row = i0 + wm * 64 + mf * 16 + quad * 4;
            #pragma unroll
            for (int r = 0; r < 4; r++)
                atomicAdd(&Yt[(size_t)(row + r) * D + col], acc[mf][nf][r]);
        }
    }
}

// ---------------- kernel: final projection out = relu((tmp+cst|0) @ Wp^T + bp) ----------------
__global__ __launch_bounds__(256) void proj_p(const float* __restrict__ tmp,
                                              const float* __restrict__ cst,
                                              const bf16* __restrict__ Wpb,
                                              const float* __restrict__ bp,
                                              const int* __restrict__ lb,
                                              float* __restrict__ out) {
    const int o0 = blockIdx.x * 128;
    const int i0 = blockIdx.y * 128;
    __shared__ bf16 As[128 * 32];
    __shared__ bf16 Bs[128 * 32];
    const int tid = threadIdx.x;
    const int lane = tid & 63;
    const int w = tid >> 6;
    const int wm = w & 1, wn = w >> 1;
    const int fr = lane & 15, quad = lane >> 4;
    const int ar = tid >> 1;
    const int ac = (tid & 1) * 16;
    const int g = i0 + ar;
    const bool live = lb[g + 1] - lb[g] > 0;
    const float* tp = tmp + (size_t)g * D + ac;
    const float* cp = cst + ac;
    const bf16* gB = Wpb + (size_t)(o0 + w * 32 + (lane >> 2)) * D + (lane & 3) * 8;
    bf16* lB = Bs + (w * 32) * 32;

    f32x4 acc[4][4] = {};

    for (int kt = 0; kt < D; kt += 32) {
        __syncthreads();
        gload_lds16(gB + kt, lB);
        gload_lds16(gB + (size_t)16 * D + kt, lB + 16 * 32);
        {
            float4 x0 = *(const float4*)(tp + kt);
            float4 x1 = *(const float4*)(tp + kt + 4);
            float4 x2 = *(const float4*)(tp + kt + 8);
            float4 x3 = *(const float4*)(tp + kt + 12);
            float4 c0 = *(const float4*)(cp + kt);
            float4 c1 = *(const float4*)(cp + kt + 4);
            float4 c2 = *(const float4*)(cp + kt + 8);
            float4 c3 = *(const float4*)(cp + kt + 12);
            float s = live ? 1.f : 0.f;
            bf16x8 v0 = {(bf16)((x0.x+c0.x)*s),(bf16)((x0.y+c0.y)*s),(bf16)((x0.z+c0.z)*s),(bf16)((x0.w+c0.w)*s),
                         (bf16)((x1.x+c1.x)*s),(bf16)((x1.y+c1.y)*s),(bf16)((x1.z+c1.z)*s),(bf16)((x1.w+c1.w)*s)};
            bf16x8 v1 = {(bf16)((x2.x+c2.x)*s),(bf16)((x2.y+c2.y)*s),(bf16)((x2.z+c2.z)*s),(bf16)((x2.w+c2.w)*s),
                         (bf16)((x3.x+c3.x)*s),(bf16)((x3.y+c3.y)*s),(bf16)((x3.z+c3.z)*s),(bf16)((x3.w+c3.w)*s)};
            *(bf16x8*)(As + ar * 32 + ac) = v0;
            *(bf16x8*)(As + ar * 32 + ac + 8) = v1;
        }
        __syncthreads();
        bf16x8 fa[4], fb[4];
        #pragma unroll
        for (int mf = 0; mf < 4; mf++)
            fa[mf] = *(const bf16x8*)(As + (wm * 64 + mf * 16 + fr) * 32 + quad * 8);
        #pragma unroll
        for (int nf = 0; nf < 4; nf++)
            fb[nf] = *(const bf16x8*)(Bs + (wn * 64 + nf * 16 + fr) * 32 + quad * 8);
        #pragma unroll
        for (int mf = 0; mf < 4; mf++)
            #pragma unroll
            for (int nf = 0; nf < 4; nf++)
                acc[mf][nf] = __builtin_amdgcn_mfma_f32_16x16x32_bf16(fa[mf], fb[nf], acc[mf][nf], 0, 0, 0);
    }
    #pragma unroll
    for (int nf = 0; nf < 4; nf++) {
        const int col = o0 + wn * 64 + nf * 16 + fr;
        const float bs = bp[col];
        #pragma unroll
        for (int mf = 0; mf < 4; mf++) {
            const int row = i0 + wm * 64 + mf * 16 + quad * 4;
            #pragma unroll
            for (int r = 0; r < 4; r++)
                out[(size_t)(row + r) * D + col] = fmaxf(acc[mf][nf][r] + bs, 0.f);
        }
    }
}

extern "C" void kernel_launch(void* const* d_in, const int* in_sizes, int n_in,
                              void* d_out, int out_size, void* d_ws, size_t ws_size,
                              hipStream_t stream) {
    const float* nf    = (const float*)d_in[0];
    const int*   batch = (const int*)d_in[1];
    const float* gq    = (const float*)d_in[2];
    const float* wq    = (const float*)d_in[3];
    const float* bq    = (const float*)d_in[4];
    const float* wk    = (const float*)d_in[5];
    const float* bk    = (const float*)d_in[6];
    const float* wv    = (const float*)d_in[7];
    const float* bv    = (const float*)d_in[8];
    const float* wo    = (const float*)d_in[9];
    const float* bo    = (const float*)d_in[10];
    const float* wp    = (const float*)d_in[11];
    const float* bp    = (const float*)d_in[12];
    float* out = (float*)d_out;

    // workspace layout (~129.4 MiB):
    // [0, 64Mi): Abf during cvt_a..k_gemm; afterwards recycled:
    //   Wbar [0,2Mi) | abar [2,6Mi) | Wov [6,10Mi) | tmp [10,11Mi) | cst [11Mi,+4K)
    // [64Mi,128Mi): Kb.  [128Mi, ...): lb, udata, Wkb, Wpb, P2.
    char* ws = (char*)d_ws;
    bf16*  Abf  = (bf16*)ws;
    float* Wbar = (float*)ws;
    bf16*  abar = (bf16*)(ws + ((size_t)2 << 20));
    bf16*  Wov  = (bf16*)(ws + ((size_t)6 << 20));
    float* tmp  = (float*)(ws + ((size_t)10 << 20));
    float* cst  = (float*)(ws + ((size_t)11 << 20));
    bf16*  Kb   = (bf16*)(ws + ((size_t)64 << 20));
    char* sm = ws + ((size_t)128 << 20);
    int*  lb    = (int*)sm;    sm += 4096;
    int*  udata = (int*)sm;    sm += (size_t)NUM_GRAPHS * USTRIDE * 4 + 2048;
    bf16* Wkb   = (bf16*)sm;   sm += (size_t)D * D * 2;
    bf16* Wpb   = (bf16*)sm;   sm += (size_t)D * D * 2;
    float* P2   = (float*)sm;  sm += (size_t)64 * D * 4;

    lb_kernel<<<3, 256, 0, stream>>>(batch, lb);
    dedup_kernel<<<NUM_GRAPHS, 192, 0, stream>>>(lb, udata);
    cvt_kernel<<<(D * D / 4) / 256, 256, 0, stream>>>(wk, Wkb, D * D);
    cvt_kernel<<<(D * D / 4) / 256, 256, 0, stream>>>(wp, Wpb, D * D);
    p2_kernel<<<dim3(8, 8), 256, 0, stream>>>(gq, wq, P2);
    cvt_kernel<<<(N_NODES * D / 4) / 256, 256, 0, stream>>>(nf, Abf, N_NODES * D);
    k_gemm<<<dim3(N_NODES / 128, 4), 256, 0, stream>>>(Abf, Wkb, bk, Kb);
    // Abf dead; its region now holds Wbar/abar/Wov/tmp/cst
    wov_kernel<<<dim3(16, 8), 256, 0, stream>>>(wo, wv, Wov);
    cst_kernel<<<2, 256, 0, stream>>>(wo, bv, bo, cst);
    attn_kernel<<<dim3(2, NUM_GRAPHS), 256, 0, stream>>>(Kb, P2, bq, lb, udata, Wbar);
    abar_kernel<<<NUM_GRAPHS, 256, 0, stream>>>(nf, Wbar, lb, abar);
    zero_kernel<<<(NUM_GRAPHS * D / 4 + 255) / 256, 256, 0, stream>>>(tmp, NUM_GRAPHS * D / 4);
    og_gemm<<<dim3(4, 4, 8), 256, 0, stream>>>(abar, Wov, tmp);
    proj_p<<<dim3(4, 4), 256, 0, stream>>>(tmp, cst, Wpb, bp, lb, out);
}